// Round 1
// 1687.525 us; speedup vs baseline: 1.2504x; 1.2504x over previous
//
#include <hip/hip_runtime.h>
#include <math.h>

// -------------------------------------------------------------------------
// VQ-VAE forward, fp32, round 22: decoder 3x3 convs moved to MFMA bf16x2.
//  - conv3_mfma: implicit-GEMM 3x3 conv via mfma_f32_16x16x32_bf16,
//    split-precision (hi+lo bf16, 3 passes) ~ fp32 accuracy, fp32 accum.
//  - Weights prepacked per call into A-fragment order (prep_w3) in C's
//    free region (C is dead after the pre 1x1 conv).
//  - Encoder + up0 stay fp32 VALU (VQ argmin tie-flip risk; convert later
//    once decoder absmax sensitivity is measured).
// Workspace: A(64MB) B(32MB) C(32MB); cb64/cbn64 in A tail; wpk in C.
// -------------------------------------------------------------------------

#define DEV __device__ __forceinline__

DEV int rfl(int v) { return __builtin_amdgcn_readfirstlane(v); }

DEV void async_copy16(const float* g, float* l) {
  __builtin_amdgcn_global_load_lds(
      (const __attribute__((address_space(1))) void*)g,
      (__attribute__((address_space(3))) void*)l, 16, 0, 0);
}

typedef __attribute__((ext_vector_type(8))) short bf16x8;
typedef __attribute__((ext_vector_type(4))) float f32x4;

DEV ushort f2bf(float f) {           // fp32 -> bf16 round-to-nearest-even
  uint u = __float_as_uint(f);
  u += 0x7fffu + ((u >> 16) & 1u);
  return (ushort)(u >> 16);
}
DEV float bf2f(ushort h) { return __uint_as_float(((uint)h) << 16); }

// ---------------- weight prepack for conv3_mfma ---------------------------
// Layout: [khkw 9][ch CIN/32][m COT/16][lane 64][hi8 | lo8] bf16.
// Lane l holds A[row = l&15][k = (l>>4)*8 + i] (row=co in tile, k=ci in chunk).
template<int CIN, int COT>
__global__ __launch_bounds__(256) void prep_w3(
    const float* __restrict__ w, ushort* __restrict__ wpk) {
  constexpr int nCh = CIN / 32, nM = COT / 16;
  const int t = blockIdx.x * 256 + threadIdx.x;
  if (t >= 9 * nCh * nM * 64) return;
  const int l = t & 63;
  int q = t >> 6;
  const int m = q % nM;  q /= nM;
  const int ch = q % nCh; q /= nCh;
  const int khkw = q;
  const int co = m * 16 + (l & 15);
  const int k8 = (l >> 4) * 8;
  ushort* o = wpk + (size_t)t * 16;
#pragma unroll
  for (int i = 0; i < 8; i++) {
    const int ci = ch * 32 + k8 + i;
    const float v = w[((size_t)co * CIN + ci) * 9 + khkw];
    const ushort hi = f2bf(v);
    o[i]     = hi;
    o[8 + i] = f2bf(v - bf2f(hi));
  }
}

// ---------------- conv 3x3 s1 p1 via MFMA bf16x2 (64x64 imgs) -------------
// Block = 1 output row x all COT. 4 waves x 16 positions each.
// LDS: [buf 2][plane hi/lo][rowrel 3][posslot 66][ci 32 bf16 + 8 pad] (80B slots).
// Per ci-chunk(32) x (kh,kw): B-frag = 1 ds_read_b128/plane; A-frags from
// prepacked global (L2-resident); 3 mfma per (m, khkw).
template<int CIN, int COT, bool RELU_IN>
__global__ __launch_bounds__(256, 2) void conv3_mfma(
    const float* __restrict__ x, const ushort* __restrict__ wpk,
    const float* __restrict__ bias, float* __restrict__ y) {
  constexpr int nCh = CIN / 32, nM = COT / 16;
  __shared__ ushort lds[2][2][3 * 66 * 40];   // 63,360 B
  const int tid = threadIdx.x;
  const int l = tid & 63;
  const int wv = rfl(tid >> 6);               // 0..3
  const int r = blockIdx.x;                   // output row 0..63
  const int n = blockIdx.z;

  // zero the pad columns (posslot 0 and 65) once, both buffers/planes
  {
    uint* lp = (uint*)&lds[0][0][0];
    for (int s = tid; s < 24 * 20; s += 256) {
      const int slot = s / 20, w32 = s % 20;
      const int which = slot & 1;             // 0 -> slot0, 1 -> slot65
      const int rowrel = (slot >> 1) % 3;
      const int plane  = ((slot >> 1) / 3) & 1;
      const int buf    = (slot >> 1) / 6;
      lp[(size_t)((buf * 2 + plane) * 198 + rowrel * 66 + (which ? 65 : 0)) * 20 + w32] = 0;
    }
  }

  const float* xn = x + ((size_t)n * CIN) * 4096;

  // staging regs: [rowrel][cc][pair]; ci = ch*32 + cc*8 + wv*2 + {0,1}
  float sreg[3][4][2];
  auto LOADG = [&](int ch) {
#pragma unroll
    for (int rr = 0; rr < 3; rr++) {
      const int ir = r - 1 + rr;
      const bool ok = (ir >= 0) && (ir < 64);
#pragma unroll
      for (int cc = 0; cc < 4; cc++) {
        const int ci0 = ch * 32 + cc * 8 + wv * 2;
        sreg[rr][cc][0] = ok ? xn[((size_t)ci0 * 64 + ir) * 64 + l] : 0.f;
        sreg[rr][cc][1] = ok ? xn[((size_t)(ci0 + 1) * 64 + ir) * 64 + l] : 0.f;
      }
    }
  };
  auto WRITE = [&](int buf) {
    uint* ph = (uint*)&lds[buf][0][0];
    uint* pl = (uint*)&lds[buf][1][0];
#pragma unroll
    for (int rr = 0; rr < 3; rr++) {
#pragma unroll
      for (int cc = 0; cc < 4; cc++) {
        float v0 = sreg[rr][cc][0], v1 = sreg[rr][cc][1];
        if (RELU_IN) { v0 = fmaxf(v0, 0.f); v1 = fmaxf(v1, 0.f); }
        const ushort h0 = f2bf(v0), h1 = f2bf(v1);
        const ushort l0 = f2bf(v0 - bf2f(h0)), l1 = f2bf(v1 - bf2f(h1));
        const int idx = (rr * 66 + (l + 1)) * 20 + cc * 4 + wv;   // u32 index
        ph[idx] = (uint)h0 | ((uint)h1 << 16);
        pl[idx] = (uint)l0 | ((uint)l1 << 16);
      }
    }
  };

  f32x4 acc[nM];
#pragma unroll
  for (int m = 0; m < nM; m++) {
    const int co = m * 16 + ((l >> 4) << 2);
    acc[m] = (f32x4){bias[co], bias[co + 1], bias[co + 2], bias[co + 3]};
  }

  const int pb = wv * 16;          // this wave's position base
  LOADG(0); WRITE(0);
  if (nCh > 1) LOADG(1);
  int cur = 0;
  for (int ch = 0; ch < nCh; ch++) {
    __syncthreads();               // buf[cur] writes visible everywhere
    const ushort* base_h = &lds[cur][0][0];
    const ushort* base_l = &lds[cur][1][0];
#pragma unroll
    for (int kh = 0; kh < 3; kh++) {
#pragma unroll
      for (int kw = 0; kw < 3; kw++) {
        const int slot = kh * 66 + pb + (l & 15) + kw;
        const bf16x8 bh = *(const bf16x8*)(base_h + slot * 40 + (l >> 4) * 8);
        const bf16x8 bl = *(const bf16x8*)(base_l + slot * 40 + (l >> 4) * 8);
        const ushort* wp = wpk + ((((size_t)(kh * 3 + kw) * nCh + ch) * nM) * 64 + l) * 16;
#pragma unroll
        for (int m = 0; m < nM; m++) {
          const bf16x8 ah = *(const bf16x8*)(wp + (size_t)m * 64 * 16);
          const bf16x8 al = *(const bf16x8*)(wp + (size_t)m * 64 * 16 + 8);
          acc[m] = __builtin_amdgcn_mfma_f32_16x16x32_bf16(ah, bh, acc[m], 0, 0, 0);
          acc[m] = __builtin_amdgcn_mfma_f32_16x16x32_bf16(al, bh, acc[m], 0, 0, 0);
          acc[m] = __builtin_amdgcn_mfma_f32_16x16x32_bf16(ah, bl, acc[m], 0, 0, 0);
        }
      }
    }
    if (ch + 1 < nCh) {
      WRITE(cur ^ 1);                       // consume sreg (chunk ch+1)
      if (ch + 2 < nCh) LOADG(ch + 2);      // issue next loads early
    }
    cur ^= 1;
  }

  const int pos = pb + (l & 15);
  const int r4 = (l >> 4) << 2;
#pragma unroll
  for (int m = 0; m < nM; m++) {
    const int co = m * 16 + r4;
    float* yp = y + (((size_t)(n * COT + co)) * 64 + r) * 64 + pos;
#pragma unroll
    for (int j = 0; j < 4; j++) yp[(size_t)j * 4096] = acc[m][j];
  }
}

// ---------------- conv 4x4 stride2 pad1 (generic, used for conv0) ---------
template<int CIN, int COT, bool RELU_OUT, int OW>
__global__ __launch_bounds__(256) void conv4s2_row(
    const float* __restrict__ x, const float* __restrict__ w,
    const float* __restrict__ bias, float* __restrict__ y,
    int Hout, int Cout) {
  const int Win = OW * 2, Hin = Hout * 2;
  const int t = blockIdx.x * 256 + threadIdx.x;
  const int wo = t & (OW - 1);
  const int ho = rfl(t / OW);
  const int co0 = blockIdx.y * COT, n = blockIdx.z;

  float acc[COT];
#pragma unroll
  for (int u = 0; u < COT; u++) acc[u] = bias[co0 + u];

  const int iw0 = 2 * wo - 1;
  const int cA = iw0 < 0 ? 0 : iw0;
  const bool mA = iw0 >= 0;
  const int cD = (iw0 + 3 < Win) ? iw0 + 3 : Win - 1;
  const bool mD = iw0 + 3 < Win;

  for (int ci = 0; ci < CIN; ci++) {
    const float* xp = x + ((size_t)(n * CIN + ci)) * Hin * Win;
    const float* wp = w + ((size_t)(co0 * CIN + ci)) * 16;
#pragma unroll
    for (int kh = 0; kh < 4; kh++) {
      const int ih = 2 * ho - 1 + kh;
      if (ih >= 0 && ih < Hin) {
        const float* row = xp + (size_t)ih * Win;
        float x0 = row[cA];      x0 = mA ? x0 : 0.f;
        float x1 = row[iw0 + 1];
        float x2 = row[iw0 + 2];
        float x3 = row[cD];      x3 = mD ? x3 : 0.f;
#pragma unroll
        for (int u = 0; u < COT; u++) {
          const float* wr = wp + u * CIN * 16 + kh * 4;
          acc[u] = fmaf(x0, wr[0], acc[u]);
          acc[u] = fmaf(x1, wr[1], acc[u]);
          acc[u] = fmaf(x2, wr[2], acc[u]);
          acc[u] = fmaf(x3, wr[3], acc[u]);
        }
      }
    }
  }
#pragma unroll
  for (int u = 0; u < COT; u++) {
    float v = acc[u];
    if (RELU_OUT) v = fmaxf(v, 0.f);
    y[(((size_t)(n * Cout + co0 + u)) * Hout + ho) * OW + wo] = v;
  }
}

// ---------------- conv 4x4 s2 p1, 128^2 -> 64^2, async DMA, 2-img batch ---
template<int CIN, int COT, bool RELU_OUT>
__global__ __launch_bounds__(256, 4) void conv4s2_async_b2(
    const float* __restrict__ x, const float* __restrict__ w,
    const float* __restrict__ bias, float* __restrict__ y, int Cout) {
  __shared__ float xs[2][2 * 20 * 128];   // 2 x 20 KB
  const int tid = threadIdx.x;
  const int lane = tid & 63;
  const int wv = rfl(tid >> 6);           // 0..3
  const int r0 = blockIdx.x * 8;          // first output row (0..56)
  const int co0 = blockIdx.y * COT;
  const int n0 = blockIdx.z * 2;

  int gofs[5];
#pragma unroll
  for (int i = 0; i < 5; i++) {
    const int q = tid + i * 256;
    const int img = q / 640;
    const int r = q - img * 640;
    const int rr = r >> 5, f4 = r & 31;
    int grow = 2 * r0 - 2 + rr;
    grow = grow < 0 ? 0 : (grow > 127 ? 127 : grow);
    gofs[i] = img * CIN * 16384 + grow * 128 + f4 * 4;
  }
  const float* xn = x + ((size_t)(n0 * CIN)) * 16384;

  float accA[2 * COT], accB[2 * COT];
#pragma unroll
  for (int u = 0; u < COT; u++) {
    const float b = bias[co0 + u];
    accA[u] = b; accA[COT + u] = b;
    accB[u] = b; accB[COT + u] = b;
  }

  const bool mm = lane > 0;
  const bool mp = lane < 63;
  const bool invLo = (r0 == 0)  && (wv == 0);
  const bool invHi = (r0 == 56) && (wv == 3);

  {
    float* lb = &xs[0][0];
#pragma unroll
    for (int i = 0; i < 5; i++)
      async_copy16(xn + gofs[i], lb + (tid + i * 256) * 4);
  }

  int cur = 0;
  for (int ci = 0; ci < CIN; ci++) {
    __syncthreads();
    if (ci + 1 < CIN) {
      const float* xc = xn + (size_t)(ci + 1) * 16384;
      float* lb = &xs[cur ^ 1][0];
#pragma unroll
      for (int i = 0; i < 5; i++)
        async_copy16(xc + gofs[i], lb + (tid + i * 256) * 4);
    }
    const float* xb = xs[cur];
    float em[2][6], ee[2][6], oo[2][6], ep[2][6];
#pragma unroll
    for (int img = 0; img < 2; img++) {
#pragma unroll
      for (int d = 0; d < 6; d++) {
        const float* rp = xb + img * 2560 + (4 * wv + 1 + d) * 128;
        float e = rp[2 * lane];
        float o = rp[2 * lane + 1];
        float m = mm ? rp[2 * lane - 1] : 0.f;
        float p = mp ? rp[2 * lane + 2] : 0.f;
        em[img][d] = m; ee[img][d] = e; oo[img][d] = o; ep[img][d] = p;
      }
      if (invLo) { em[img][0] = 0.f; ee[img][0] = 0.f; oo[img][0] = 0.f; ep[img][0] = 0.f; }
      if (invHi) { em[img][5] = 0.f; ee[img][5] = 0.f; oo[img][5] = 0.f; ep[img][5] = 0.f; }
    }
#pragma unroll
    for (int u = 0; u < COT; u++) {
      const float* wr = w + ((size_t)((co0 + u) * CIN + ci)) * 16;  // s_load
#pragma unroll
      for (int kh = 0; kh < 4; kh++) {
        const float w0 = wr[kh * 4 + 0];
        const float w1 = wr[kh * 4 + 1];
        const float w2 = wr[kh * 4 + 2];
        const float w3 = wr[kh * 4 + 3];
#pragma unroll
        for (int img = 0; img < 2; img++) {
          const int o = img * COT + u;
          accA[o] = fmaf(em[img][kh],     w0, accA[o]);
          accA[o] = fmaf(ee[img][kh],     w1, accA[o]);
          accA[o] = fmaf(oo[img][kh],     w2, accA[o]);
          accA[o] = fmaf(ep[img][kh],     w3, accA[o]);
          accB[o] = fmaf(em[img][kh + 2], w0, accB[o]);
          accB[o] = fmaf(ee[img][kh + 2], w1, accB[o]);
          accB[o] = fmaf(oo[img][kh + 2], w2, accB[o]);
          accB[o] = fmaf(ep[img][kh + 2], w3, accB[o]);
        }
      }
    }
    cur ^= 1;
  }
  const int roA = r0 + 2 * wv;
#pragma unroll
  for (int img = 0; img < 2; img++) {
#pragma unroll
    for (int u = 0; u < COT; u++) {
      const int o = img * COT + u;
      float vA = accA[o], vB = accB[o];
      if (RELU_OUT) { vA = fmaxf(vA, 0.f); vB = fmaxf(vB, 0.f); }
      float* yp = y + (((size_t)((n0 + img) * Cout + co0 + u)) * 64 + roA) * 64 + lane;
      yp[0]  = vA;
      yp[64] = vB;
    }
  }
}

// ---------------- conv 3x3 s1 p1, async DMA, 2-image batch ----------------
template<int CIN, int COT, bool RELU_IN>
__global__ __launch_bounds__(256, 4) void conv3_async_b2(
    const float* __restrict__ x, const float* __restrict__ w,
    const float* __restrict__ bias, float* __restrict__ y, int Cout) {
  __shared__ float xs[2][2 * 4 * 10 * 64];   // 2 x 20 KB
  const int tid = threadIdx.x;
  const int lane = tid & 63;
  const int wv = rfl(tid >> 6);              // 0..3
  const int r0 = blockIdx.x * 8;
  const int co0 = blockIdx.y * COT;
  const int n0 = blockIdx.z * 2;

  int gofs[5];
#pragma unroll
  for (int i = 0; i < 5; i++) {
    const int q = tid + i * 256;
    const int img = q / 640;
    const int r = q - img * 640;
    const int ci = r / 160;
    const int rem = r - ci * 160;
    const int rr = rem >> 4, f4 = rem & 15;
    int grow = r0 - 1 + rr;
    grow = grow < 0 ? 0 : (grow > 63 ? 63 : grow);
    gofs[i] = img * CIN * 4096 + ci * 4096 + grow * 64 + f4 * 4;
  }
  const float* xn = x + ((size_t)(n0 * CIN)) * 4096;

  float acc0[2 * COT], acc1[2 * COT];
#pragma unroll
  for (int u = 0; u < COT; u++) {
    const float b = bias[co0 + u];
    acc0[u] = b; acc0[COT + u] = b;
    acc1[u] = b; acc1[COT + u] = b;
  }

  const int lm = lane > 0 ? lane - 1 : 0;
  const bool mm = lane > 0;
  const int lp = lane < 63 ? lane + 1 : 63;
  const bool mp = lane < 63;
  const bool inv0 = (r0 == 0) && (wv == 0);
  const bool inv3 = (r0 == 56) && (wv == 3);

  {
    float* lb = &xs[0][0];
#pragma unroll
    for (int i = 0; i < 5; i++)
      async_copy16(xn + gofs[i], lb + (tid + i * 256) * 4);
  }

  int cur = 0;
  for (int c0 = 0; c0 < CIN; c0 += 4) {
    __syncthreads();
    if (c0 + 4 < CIN) {
      const float* xc = xn + (size_t)(c0 + 4) * 4096;
      float* lb = &xs[cur ^ 1][0];
#pragma unroll
      for (int i = 0; i < 5; i++)
        async_copy16(xc + gofs[i], lb + (tid + i * 256) * 4);
    }
    const float* xb = xs[cur];
#pragma unroll
    for (int ci = 0; ci < 4; ci++) {
      float a[2][4], v[2][4], b[2][4];
#pragma unroll
      for (int img = 0; img < 2; img++) {
#pragma unroll
        for (int d = 0; d < 4; d++) {
          const float* rp = xb + ((img * 4 + ci) * 10 + (wv << 1) + d) * 64;
          float aa = rp[lm]; aa = mm ? aa : 0.f;
          float vv = rp[lane];
          float bb = rp[lp]; bb = mp ? bb : 0.f;
          if (RELU_IN) { aa = fmaxf(aa, 0.f); vv = fmaxf(vv, 0.f); bb = fmaxf(bb, 0.f); }
          a[img][d] = aa; v[img][d] = vv; b[img][d] = bb;
        }
        if (inv0) { a[img][0] = 0.f; v[img][0] = 0.f; b[img][0] = 0.f; }
        if (inv3) { a[img][3] = 0.f; v[img][3] = 0.f; b[img][3] = 0.f; }
      }
      const float* wb = w + ((size_t)(co0 * CIN + c0 + ci)) * 9;
#pragma unroll
      for (int u = 0; u < COT; u++) {
        const float* wr = wb + u * CIN * 9;    // uniform -> s_load
#pragma unroll
        for (int kh = 0; kh < 3; kh++) {
          const float w0 = wr[kh * 3 + 0];
          const float w1 = wr[kh * 3 + 1];
          const float w2 = wr[kh * 3 + 2];
#pragma unroll
          for (int img = 0; img < 2; img++) {
            acc0[img * COT + u] = fmaf(a[img][kh],     w0, acc0[img * COT + u]);
            acc0[img * COT + u] = fmaf(v[img][kh],     w1, acc0[img * COT + u]);
            acc0[img * COT + u] = fmaf(b[img][kh],     w2, acc0[img * COT + u]);
            acc1[img * COT + u] = fmaf(a[img][kh + 1], w0, acc1[img * COT + u]);
            acc1[img * COT + u] = fmaf(v[img][kh + 1], w1, acc1[img * COT + u]);
            acc1[img * COT + u] = fmaf(b[img][kh + 1], w2, acc1[img * COT + u]);
          }
        }
      }
    }
    cur ^= 1;
  }
  const int ro = r0 + (wv << 1);
#pragma unroll
  for (int img = 0; img < 2; img++) {
#pragma unroll
    for (int u = 0; u < COT; u++) {
      float* yp = y + (((size_t)((n0 + img) * Cout + co0 + u)) * 64 + ro) * 64 + lane;
      yp[0]  = acc0[img * COT + u];
      yp[64] = acc1[img * COT + u];
    }
  }
}

// ---------------- conv 3x3 s1 p1, async DMA, 4-row tile (enc res) ---------
template<int CIN, int COT, bool RELU_IN>
__global__ __launch_bounds__(256, 4) void conv3_async2(
    const float* __restrict__ x, const float* __restrict__ w,
    const float* __restrict__ bias, float* __restrict__ y, int Cout) {
  __shared__ float xs[2][8 * 6 * 64];     // 2 x 12 KB
  const int tid = threadIdx.x;
  const int lane = tid & 63;
  const int wv = rfl(tid >> 6);           // 0..3 = output row within tile
  const int r0 = blockIdx.x * 4;
  const int co0 = blockIdx.y * COT;
  const int n = blockIdx.z;

  int gofs[3];
#pragma unroll
  for (int i = 0; i < 3; i++) {
    const int q = tid + i * 256;          // 768 = 8ci x 6rows x 16 f4
    const int ci = q / 96, rem = q - ci * 96;
    const int rr = rem >> 4, f4 = rem & 15;
    int grow = r0 - 1 + rr;
    grow = grow < 0 ? 0 : (grow > 63 ? 63 : grow);
    gofs[i] = ci * 4096 + grow * 64 + f4 * 4;
  }

  const float* xn = x + ((size_t)(n * CIN)) * 4096;

  float acc[COT];
#pragma unroll
  for (int u = 0; u < COT; u++) acc[u] = bias[co0 + u];

  const int lm = lane > 0 ? lane - 1 : 0;
  const bool mm = lane > 0;
  const int lp = lane < 63 ? lane + 1 : 63;
  const bool mp = lane < 63;
  const bool inv0 = (r0 == 0)  && (wv == 0);
  const bool inv2 = (r0 == 60) && (wv == 3);

  {
    float* lb = &xs[0][0];
#pragma unroll
    for (int i = 0; i < 3; i++)
      async_copy16(xn + gofs[i], lb + (tid + i * 256) * 4);
  }

  int cur = 0;
  for (int c0 = 0; c0 < CIN; c0 += 8) {
    __syncthreads();
    if (c0 + 8 < CIN) {
      const float* xc = xn + (size_t)(c0 + 8) * 4096;
      float* lb = &xs[cur ^ 1][0];
#pragma unroll
      for (int i = 0; i < 3; i++)
        async_copy16(xc + gofs[i], lb + (tid + i * 256) * 4);
    }
    const float* xb = xs[cur];
#pragma unroll
    for (int ci = 0; ci < 8; ci++) {
      float a[3], v[3], b[3];
#pragma unroll
      for (int kh = 0; kh < 3; kh++) {
        const float* rp = xb + (ci * 6 + wv + kh) * 64;
        float aa = rp[lm]; aa = mm ? aa : 0.f;
        float vv = rp[lane];
        float bb = rp[lp]; bb = mp ? bb : 0.f;
        if (RELU_IN) { aa = fmaxf(aa, 0.f); vv = fmaxf(vv, 0.f); bb = fmaxf(bb, 0.f); }
        a[kh] = aa; v[kh] = vv; b[kh] = bb;
      }
      if (inv0) { a[0] = 0.f; v[0] = 0.f; b[0] = 0.f; }
      if (inv2) { a[2] = 0.f; v[2] = 0.f; b[2] = 0.f; }
      const float* wb = w + ((size_t)(co0 * CIN + c0 + ci)) * 9;
#pragma unroll
      for (int u = 0; u < COT; u++) {
        const float* wr = wb + u * CIN * 9;      // uniform -> s_load
#pragma unroll
        for (int kh = 0; kh < 3; kh++) {
          acc[u] = fmaf(a[kh], wr[kh * 3 + 0], acc[u]);
          acc[u] = fmaf(v[kh], wr[kh * 3 + 1], acc[u]);
          acc[u] = fmaf(b[kh], wr[kh * 3 + 2], acc[u]);
        }
      }
    }
    cur ^= 1;
  }
  const int ro = r0 + wv;
#pragma unroll
  for (int u = 0; u < COT; u++)
    y[(((size_t)(n * Cout + co0 + u)) * 64 + ro) * 64 + lane] = acc[u];
}

// ---------------- conv 1x1 v4: 4 positions per thread ---------------------
template<int CIN, int COT, bool RELU_IN, bool ACCUM, bool RELU_OUT>
__global__ __launch_bounds__(256) void conv1x1_v4(
    const float* __restrict__ x, const float* __restrict__ w,
    const float* __restrict__ bias, float* __restrict__ y,
    int HW, int Cout) {
  const int p = (blockIdx.x * 256 + threadIdx.x) * 4;
  const int co0 = blockIdx.y * COT, n = blockIdx.z;

  float4 acc[COT];
#pragma unroll
  for (int u = 0; u < COT; u++) {
    const float b = bias[co0 + u];
    acc[u] = make_float4(b, b, b, b);
  }
  for (int ci = 0; ci < CIN; ci++) {
    float4 xv = *(const float4*)&x[((size_t)(n * CIN + ci)) * HW + p];
    if (RELU_IN) {
      xv.x = fmaxf(xv.x, 0.f); xv.y = fmaxf(xv.y, 0.f);
      xv.z = fmaxf(xv.z, 0.f); xv.w = fmaxf(xv.w, 0.f);
    }
#pragma unroll
    for (int u = 0; u < COT; u++) {
      const float wv = w[(co0 + u) * CIN + ci];
      acc[u].x = fmaf(xv.x, wv, acc[u].x);
      acc[u].y = fmaf(xv.y, wv, acc[u].y);
      acc[u].z = fmaf(xv.z, wv, acc[u].z);
      acc[u].w = fmaf(xv.w, wv, acc[u].w);
    }
  }
#pragma unroll
  for (int u = 0; u < COT; u++) {
    float4* yp = (float4*)&y[((size_t)(n * Cout + co0 + u)) * HW + p];
    float4 r = acc[u];
    if (ACCUM) {
      float4 h = *yp;
      r.x += h.x; r.y += h.y; r.z += h.z; r.w += h.w;
    }
    if (RELU_OUT) {
      r.x = fmaxf(r.x, 0.f); r.y = fmaxf(r.y, 0.f);
      r.z = fmaxf(r.z, 0.f); r.w = fmaxf(r.w, 0.f);
    }
    *yp = r;
  }
}

// ---------------- ConvTranspose 4x4 s2 p1, 64->128, async, 4-img batch ----
template<int CIN, int COT, bool RELU_IN, bool RELU_OUT>
__global__ __launch_bounds__(256, 4) void convt_async_b4(
    const float* __restrict__ x, const float* __restrict__ w,
    const float* __restrict__ bias, float* __restrict__ y, int Cout) {
  __shared__ float xs[2][4 * 2 * 6 * 64];   // 2 x 12 KB
  const int tid = threadIdx.x;
  const int lane = tid & 63;
  const int wv = rfl(tid >> 6);             // 0..3
  const int o0 = blockIdx.x * 8;            // first output row
  const int co0 = blockIdx.y * COT;
  const int n0 = blockIdx.z * 4;
  const int i0 = (o0 >> 1) - 1;             // first staged input row

  int gofs[3];
#pragma unroll
  for (int i = 0; i < 3; i++) {
    const int q = tid + i * 256;            // 768 = 4img x 2ci x 6rows x 16f4
    const int img = q / 192;
    const int r = q - img * 192;
    const int ci = r / 96;
    const int rem = r - ci * 96;
    const int rr = rem >> 4, f4 = rem & 15;
    int grow = i0 + rr;
    grow = grow < 0 ? 0 : (grow > 63 ? 63 : grow);
    gofs[i] = img * CIN * 4096 + ci * 4096 + grow * 64 + f4 * 4;
  }
  const float* xn = x + ((size_t)(n0 * CIN)) * 4096;

  float aA0[4 * COT], aA1[4 * COT], aB0[4 * COT], aB1[4 * COT];
#pragma unroll
  for (int u = 0; u < COT; u++) {
    const float b = bias[co0 + u];
#pragma unroll
    for (int img = 0; img < 4; img++) {
      aA0[img * COT + u] = b; aA1[img * COT + u] = b;
      aB0[img * COT + u] = b; aB1[img * COT + u] = b;
    }
  }

  const int lm = lane > 0 ? lane - 1 : 0;
  const bool mm = lane > 0;
  const int lp = lane < 63 ? lane + 1 : 63;
  const bool mp = lane < 63;
  const bool invLo = (o0 == 0)   && (wv == 0);   // d=0 row is ih=-1
  const bool invHi = (o0 == 120) && (wv == 3);   // d=2 row is ih=64

  {
    float* lb = &xs[0][0];
#pragma unroll
    for (int i = 0; i < 3; i++)
      async_copy16(xn + gofs[i], lb + (tid + i * 256) * 4);
  }

  int cur = 0;
  for (int c0 = 0; c0 < CIN; c0 += 2) {
    __syncthreads();
    if (c0 + 2 < CIN) {
      const float* xc = xn + (size_t)(c0 + 2) * 4096;
      float* lb = &xs[cur ^ 1][0];
#pragma unroll
      for (int i = 0; i < 3; i++)
        async_copy16(xc + gofs[i], lb + (tid + i * 256) * 4);
    }
    const float* xb = xs[cur];
#pragma unroll
    for (int ci = 0; ci < 2; ci++) {
      float v[4][3], al[4][3], br[4][3];
#pragma unroll
      for (int img = 0; img < 4; img++) {
#pragma unroll
        for (int d = 0; d < 3; d++) {
          const float* rp = xb + ((img * 2 + ci) * 6 + wv + d) * 64;
          float vv = rp[lane];
          float aa = rp[lm]; aa = mm ? aa : 0.f;
          float bb = rp[lp]; bb = mp ? bb : 0.f;
          if (RELU_IN) { vv = fmaxf(vv, 0.f); aa = fmaxf(aa, 0.f); bb = fmaxf(bb, 0.f); }
          v[img][d] = vv; al[img][d] = aa; br[img][d] = bb;
        }
        if (invLo) { v[img][0] = 0.f; al[img][0] = 0.f; br[img][0] = 0.f; }
        if (invHi) { v[img][2] = 0.f; al[img][2] = 0.f; br[img][2] = 0.f; }
      }
      const float* wp = w + ((size_t)((c0 + ci) * Cout + co0)) * 16;
#pragma unroll
      for (int u = 0; u < COT; u++) {
        const float* wr = wp + u * 16;    // uniform -> s_load
        const float w0  = wr[0],  w1  = wr[1],  w2  = wr[2],  w3  = wr[3];
        const float w4  = wr[4],  w5  = wr[5],  w6  = wr[6],  w7  = wr[7];
        const float w8  = wr[8],  w9  = wr[9],  w10 = wr[10], w11 = wr[11];
        const float w12 = wr[12], w13 = wr[13], w14 = wr[14], w15 = wr[15];
#pragma unroll
        for (int img = 0; img < 4; img++) {
          const int o = img * COT + u;
          aA0[o] = fmaf(v[img][1],  w5,  aA0[o]);
          aA0[o] = fmaf(al[img][1], w7,  aA0[o]);
          aA0[o] = fmaf(v[img][0],  w13, aA0[o]);
          aA0[o] = fmaf(al[img][0], w15, aA0[o]);
          aA1[o] = fmaf(br[img][1], w4,  aA1[o]);
          aA1[o] = fmaf(v[img][1],  w6,  aA1[o]);
          aA1[o] = fmaf(br[img][0], w12, aA1[o]);
          aA1[o] = fmaf(v[img][0],  w14, aA1[o]);
          aB0[o] = fmaf(v[img][2],  w1,  aB0[o]);
          aB0[o] = fmaf(al[img][2], w3,  aB0[o]);
          aB0[o] = fmaf(v[img][1],  w9,  aB0[o]);
          aB0[o] = fmaf(al[img][1], w11, aB0[o]);
          aB1[o] = fmaf(br[img][2], w0,  aB1[o]);
          aB1[o] = fmaf(v[img][2],  w2,  aB1[o]);
          aB1[o] = fmaf(br[img][1], w8,  aB1[o]);
          aB1[o] = fmaf(v[img][1],  w10, aB1[o]);
        }
      }
    }
    cur ^= 1;
  }
  const int ohA = o0 + 2 * wv;
#pragma unroll
  for (int img = 0; img < 4; img++) {
#pragma unroll
    for (int u = 0; u < COT; u++) {
      const int o = img * COT + u;
      float vA0 = aA0[o], vA1 = aA1[o], vB0 = aB0[o], vB1 = aB1[o];
      if (RELU_OUT) {
        vA0 = fmaxf(vA0, 0.f); vA1 = fmaxf(vA1, 0.f);
        vB0 = fmaxf(vB0, 0.f); vB1 = fmaxf(vB1, 0.f);
      }
      float* rowA = y + (((size_t)((n0 + img) * Cout + co0 + u)) * 128 + ohA) * 128;
      ((float2*)rowA)[lane] = make_float2(vA0, vA1);
      ((float2*)(rowA + 128))[lane] = make_float2(vB0, vB1);
    }
  }
}

// ---------------- ConvTranspose 4x4 s2 p1 (generic, used for up1) ---------
template<int CIN, int COT, bool RELU_IN, bool RELU_OUT, int WH>
__global__ __launch_bounds__(256) void convt_row(
    const float* __restrict__ x, const float* __restrict__ w,
    const float* __restrict__ bias, float* __restrict__ y,
    int Hin, int Cout) {
  const int Hout = Hin * 2;
  const int t = blockIdx.x * 256 + threadIdx.x;
  const int a = t & (WH - 1);
  const int oh = rfl(t / WH);
  const int co0 = blockIdx.y * COT, n = blockIdx.z;

  float acc0[COT], acc1[COT];
#pragma unroll
  for (int u = 0; u < COT; u++) { acc0[u] = bias[co0 + u]; acc1[u] = bias[co0 + u]; }

  const int cm = a > 0 ? a - 1 : 0;
  const bool mm = a > 0;
  const int cp = a < WH - 1 ? a + 1 : WH - 1;
  const bool mp = a < WH - 1;

  const int kh0 = (oh + 1) & 1;
#pragma unroll
  for (int dh = 0; dh < 2; dh++) {
    const int kh = kh0 + 2 * dh;
    const int ih = (oh + 1 - kh) >> 1;
    if (ih >= 0 && ih < Hin) {
      for (int ci = 0; ci < CIN; ci++) {
        const float* row = x + (((size_t)(n * CIN + ci)) * Hin + ih) * WH;
        float x0  = row[a];
        float xm1 = row[cm];  xm1 = mm ? xm1 : 0.f;
        float xp1 = row[cp];  xp1 = mp ? xp1 : 0.f;
        if (RELU_IN) {
          x0 = fmaxf(x0, 0.f); xm1 = fmaxf(xm1, 0.f); xp1 = fmaxf(xp1, 0.f);
        }
        const float* wp = w + ((size_t)(ci * Cout + co0)) * 16 + kh * 4;
#pragma unroll
        for (int u = 0; u < COT; u++) {
          const float* wr = wp + u * 16;
          acc0[u] = fmaf(x0,  wr[1], acc0[u]);
          acc0[u] = fmaf(xm1, wr[3], acc0[u]);
          acc1[u] = fmaf(xp1, wr[0], acc1[u]);
          acc1[u] = fmaf(x0,  wr[2], acc1[u]);
        }
      }
    }
  }
#pragma unroll
  for (int u = 0; u < COT; u++) {
    float v0 = acc0[u], v1 = acc1[u];
    if (RELU_OUT) { v0 = fmaxf(v0, 0.f); v1 = fmaxf(v1, 0.f); }
    float* row = y + (((size_t)(n * Cout + co0 + u)) * Hout + oh) * (2 * WH);
    ((float2*)row)[a] = make_float2(v0, v1);
  }
}

// ---------------- VQ: codebook -> fp64 (+ norms), once per call -----------
__global__ __launch_bounds__(256) void cvt_cb(
    const float* __restrict__ cb, double* __restrict__ cb64,
    double* __restrict__ cbn64) {
  const int k = blockIdx.x * 256 + threadIdx.x;   // 0..511
  double s = 0.0;
  for (int d = 0; d < 64; d++) {
    const double c = (double)cb[d * 512 + k];
    cb64[k * 64 + d] = c;
    s = fma(c, c, s);
  }
  cbn64[k] = s;
}

// ---------------- VQ v3: scalar fp64 codebook, in-place quantize ----------
__global__ __launch_bounds__(256) void vq_kernel3(
    const float* __restrict__ cb, const double* __restrict__ cb64,
    const double* __restrict__ cbn64, float* __restrict__ zq) {
  __shared__ double redD[256];
  __shared__ int    redI[256];
  __shared__ int    bestIdx[64];
  const int tid = threadIdx.x;
  const int lane = tid & 63;
  const int g = rfl(tid >> 6);
  const int n = blockIdx.x >> 6, row = blockIdx.x & 63;
  float* zp = zq + ((size_t)n) * 262144 + (row << 6) + lane;

  double zr[64];
#pragma unroll
  for (int d = 0; d < 64; d++) zr[d] = (double)zp[(size_t)d * 4096];

  int best = 0;
  double bestd = 1e300;
  const double* cbk = cb64 + (size_t)g * 128 * 64;
  for (int j = 0; j < 128; j++) {
    const double* cw = cbk + j * 64;      // wave-uniform -> s_load
    double d0 = 0.0, d1 = 0.0, d2 = 0.0, d3 = 0.0;
#pragma unroll
    for (int d = 0; d < 64; d += 4) {
      d0 = fma(zr[d],     cw[d],     d0);
      d1 = fma(zr[d + 1], cw[d + 1], d1);
      d2 = fma(zr[d + 2], cw[d + 2], d2);
      d3 = fma(zr[d + 3], cw[d + 3], d3);
    }
    const int k = g * 128 + j;
    const double dist = cbn64[k] - 2.0 * ((d0 + d1) + (d2 + d3));
    if (dist < bestd) { bestd = dist; best = k; }
  }
  redD[tid] = bestd;
  redI[tid] = best;
  __syncthreads();
  if (tid < 64) {
    double bd = redD[lane];
    int bi = redI[lane];
#pragma unroll
    for (int gg = 1; gg < 4; gg++) {
      const double dd = redD[gg * 64 + lane];
      const int ii = redI[gg * 64 + lane];
      if (dd < bd || (dd == bd && ii < bi)) { bd = dd; bi = ii; }
    }
    bestIdx[lane] = bi;
  }
  __syncthreads();
  const int k = bestIdx[lane];
#pragma unroll
  for (int j = 0; j < 16; j++) {
    const int d = g * 16 + j;
    zp[(size_t)d * 4096] = cb[d * 512 + k];
  }
}

// -------------------------------------------------------------------------
extern "C" void kernel_launch(void* const* d_in, const int* in_sizes, int n_in,
                              void* d_out, int out_size, void* d_ws, size_t ws_size,
                              hipStream_t stream) {
  const float* x          = (const float*)d_in[0];
  const float* enc_w0     = (const float*)d_in[1];
  const float* enc_b0     = (const float*)d_in[2];
  const float* enc_w1     = (const float*)d_in[3];
  const float* enc_b1     = (const float*)d_in[4];
  const float* enc_wf     = (const float*)d_in[5];
  const float* enc_bf     = (const float*)d_in[6];
  const float* enc_res_w1 = (const float*)d_in[7];
  const float* enc_res_b1 = (const float*)d_in[8];
  const float* enc_res_w2 = (const float*)d_in[9];
  const float* enc_res_b2 = (const float*)d_in[10];
  const float* pre_w      = (const float*)d_in[11];
  const float* pre_b      = (const float*)d_in[12];
  const float* codebook   = (const float*)d_in[13];
  const float* dec_w      = (const float*)d_in[14];
  const float* dec_b      = (const float*)d_in[15];
  const float* dec_res_w1 = (const float*)d_in[16];
  const float* dec_res_b1 = (const float*)d_in[17];
  const float* dec_res_w2 = (const float*)d_in[18];
  const float* dec_res_b2 = (const float*)d_in[19];
  const float* up_w0      = (const float*)d_in[20];
  const float* up_b0      = (const float*)d_in[21];
  const float* up_w1      = (const float*)d_in[22];
  const float* up_b1      = (const float*)d_in[23];
  float* out = (float*)d_out;

  float* A = (float*)d_ws;         // 16,777,216 floats (64 MB)
  float* B = A + 16777216;         //  8,388,608 floats (32 MB)
  float* C = B + 8388608;          //  8,388,608 floats (32 MB)
  double* cb64  = (double*)(A + 6291456);          // 256 KB, VQ window only
  double* cbn64 = (double*)(A + 6291456 + 65536);  // 4 KB
  // prepacked decoder weights live in C (C is dead after the pre conv)
  ushort* wpk_dec = (ushort*)C;                    // 9*2*8*64*16 = 147456 ush
  ushort* wpk_r1a = wpk_dec + 147456;              // 9*4*2*64*16 =  73728 ush
  ushort* wpk_r1b = wpk_r1a + 73728;

  const dim3 blk(256);
  const int N = 16;

  // --- Encoder ---
  conv4s2_row<3, 16, true, 128><<<dim3(64, 4, N), blk, 0, stream>>>(
      x, enc_w0, enc_b0, A, 128, 64);
  conv4s2_async_b2<64, 4, true><<<dim3(8, 32, N / 2), blk, 0, stream>>>(
      A, enc_w1, enc_b1, B, 128);
  conv3_async_b2<128, 8, false><<<dim3(8, 16, N / 2), blk, 0, stream>>>(
      B, enc_wf, enc_bf, C, 128);
  conv3_async2<128, 8, true><<<dim3(16, 4, N), blk, 0, stream>>>(
      C, enc_res_w1, enc_res_b1, A, 32);
  conv1x1_v4<32, 8, true, true, false><<<dim3(4, 16, N), blk, 0, stream>>>(
      A, enc_res_w2, enc_res_b2, C, 4096, 128);
  conv3_async2<128, 8, true><<<dim3(16, 4, N), blk, 0, stream>>>(
      C, enc_res_w1 + (size_t)32 * 128 * 9, enc_res_b1 + 32, A, 32);
  conv1x1_v4<32, 8, true, true, true><<<dim3(4, 16, N), blk, 0, stream>>>(
      A, enc_res_w2 + (size_t)128 * 32, enc_res_b2 + 128, C, 4096, 128);
  // pre: C already relu'd -> z in A
  conv1x1_v4<128, 8, false, false, false><<<dim3(4, 8, N), blk, 0, stream>>>(
      C, pre_w, pre_b, A, 4096, 64);

  // --- decoder weight prepack (C free from here on) ---
  prep_w3<64, 128><<<dim3(36), blk, 0, stream>>>(dec_w, wpk_dec);
  prep_w3<128, 32><<<dim3(18), blk, 0, stream>>>(dec_res_w1, wpk_r1a);
  prep_w3<128, 32><<<dim3(18), blk, 0, stream>>>(
      dec_res_w1 + (size_t)32 * 128 * 9, wpk_r1b);

  // --- VQ (in-place on A) ---
  cvt_cb<<<dim3(2), blk, 0, stream>>>(codebook, cb64, cbn64);
  vq_kernel3<<<dim3(1024), blk, 0, stream>>>(codebook, cb64, cbn64, A);

  // --- Decoder (3x3 convs via MFMA bf16x2) ---
  conv3_mfma<64, 128, false><<<dim3(64, 1, N), blk, 0, stream>>>(
      A, wpk_dec, dec_b, B);
  conv3_mfma<128, 32, true><<<dim3(64, 1, N), blk, 0, stream>>>(
      B, wpk_r1a, dec_res_b1, A);
  conv1x1_v4<32, 8, true, true, false><<<dim3(4, 16, N), blk, 0, stream>>>(
      A, dec_res_w2, dec_res_b2, B, 4096, 128);
  conv3_mfma<128, 32, true><<<dim3(64, 1, N), blk, 0, stream>>>(
      B, wpk_r1b, dec_res_b1 + 32, A);
  conv1x1_v4<32, 8, true, true, true><<<dim3(4, 16, N), blk, 0, stream>>>(
      A, dec_res_w2 + (size_t)128 * 32, dec_res_b2 + 128, B, 4096, 128);
  // up0: B already relu'd -> A(16,64,128,128), ReLU out
  convt_async_b4<128, 2, false, true><<<dim3(16, 32, N / 4), blk, 0, stream>>>(
      B, up_w0, up_b0, A, 64);
  // up1: A -> out(16,3,256,256)
  convt_row<64, 3, false, false, 128><<<dim3(128, 1, N), blk, 0, stream>>>(
      A, up_w1, up_b1, out, 128, 3);
}

// Round 3
// 1201.021 us; speedup vs baseline: 1.7569x; 1.4051x over previous
//
#include <hip/hip_runtime.h>
#include <math.h>

// -------------------------------------------------------------------------
// VQ-VAE forward, fp32, round 24: R23 (all 3x3 convs + up0 on MFMA fp16x2)
// with the workspace-lifetime bug fixed.
//  - R23 FAILED because conv0's output is ALL of A (16*64*128*128 floats =
//    64 MB): the weight packs placed in "A's tail" and cb64 were written
//    up-front and then clobbered by conv0. Fix: launch the conv3 prepacks
//    AFTER conv1 (A is dead from then until up0), and cvt_cb right before
//    VQ (its original, proven position). No kernel-code changes vs R23.
//  - Liveness: A-tail packs (float ofs 8.39M+) written after conv1; later
//    A writers stay below: enc/dec res h1 = 2.1M, z = 4.19M, cb64 at
//    6.29M..6.36M. Last pack reader = dec-res2; up0 then rewrites full A.
//    up0's pack lives in C (dead after pre; nothing touches C afterwards).
// Remaining fp32 VALU: conv0, conv1, 1x1s, up1, VQ(fp64).
// -------------------------------------------------------------------------

#define DEV __device__ __forceinline__

DEV int rfl(int v) { return __builtin_amdgcn_readfirstlane(v); }

DEV void async_copy16(const float* g, float* l) {
  __builtin_amdgcn_global_load_lds(
      (const __attribute__((address_space(1))) void*)g,
      (__attribute__((address_space(3))) void*)l, 16, 0, 0);
}

typedef __attribute__((ext_vector_type(8))) _Float16 h16x8;
typedef __attribute__((ext_vector_type(4))) float f32x4;

DEV ushort f2h(float f) {
  _Float16 h = (_Float16)f;
  return __builtin_bit_cast(ushort, h);
}
DEV float h2f(ushort u) { return (float)__builtin_bit_cast(_Float16, u); }

// ---------------- weight prepack for conv3_mfma ---------------------------
// Layout: [khkw 9][ch CIN/32][m COT/16][lane 64][hi8 | lo8] f16 (lo*2^11).
// Lane l holds A[row = l&15 = co][k = (l>>4)*8 + i = ci-in-chunk].
template<int CIN, int COT>
__global__ __launch_bounds__(256) void prep_w3(
    const float* __restrict__ w, ushort* __restrict__ wpk) {
  constexpr int nCh = CIN / 32, nM = COT / 16;
  const int t = blockIdx.x * 256 + threadIdx.x;
  if (t >= 9 * nCh * nM * 64) return;
  const int l = t & 63;
  int q = t >> 6;
  const int m = q % nM;  q /= nM;
  const int ch = q % nCh; q /= nCh;
  const int khkw = q;
  const int co = m * 16 + (l & 15);
  const int k8 = (l >> 4) * 8;
  ushort* o = wpk + (size_t)t * 16;
#pragma unroll
  for (int i = 0; i < 8; i++) {
    const int ci = ch * 32 + k8 + i;
    const float v = w[((size_t)co * CIN + ci) * 9 + khkw];
    const ushort hi = f2h(v);
    o[i]     = hi;
    o[8 + i] = f2h((v - h2f(hi)) * 2048.0f);
  }
}

// ---------------- weight prepack for convt_mfma (4x4, w[ci][co][kh][kw]) --
// Layout: [tap kh*4+kw 16][ch CIN/32][m COT/16][lane 64][hi8 | lo8].
template<int CIN, int COT>
__global__ __launch_bounds__(256) void prep_wt(
    const float* __restrict__ w, ushort* __restrict__ wpk) {
  constexpr int nCh = CIN / 32, nM = COT / 16;
  const int t = blockIdx.x * 256 + threadIdx.x;
  if (t >= 16 * nCh * nM * 64) return;
  const int l = t & 63;
  int q = t >> 6;
  const int m = q % nM;  q /= nM;
  const int ch = q % nCh; q /= nCh;
  const int kh = q >> 2, kw = q & 3;
  const int co = m * 16 + (l & 15);
  const int k8 = (l >> 4) * 8;
  ushort* o = wpk + (size_t)t * 16;
#pragma unroll
  for (int i = 0; i < 8; i++) {
    const int ci = ch * 32 + k8 + i;
    const float v = w[(((size_t)ci * COT + co) * 4 + kh) * 4 + kw];
    const ushort hi = f2h(v);
    o[i]     = hi;
    o[8 + i] = f2h((v - h2f(hi)) * 2048.0f);
  }
}

// ---------------- conv 3x3 s1 p1 via MFMA fp16x2 (64x64 imgs) -------------
// Block = 1 output row x all COT. 4 waves x 16 positions each.
// LDS: [buf 2][plane hi/lo][rowrel 3][posslot 66][32 f16 + 8 pad] (80B slots).
template<int CIN, int COT, bool RELU_IN>
__global__ __launch_bounds__(256, 2) void conv3_mfma(
    const float* __restrict__ x, const ushort* __restrict__ wpk,
    const float* __restrict__ bias, float* __restrict__ y) {
  constexpr int nCh = CIN / 32, nM = COT / 16;
  __shared__ ushort lds[2][2][3 * 66 * 40];   // 63,360 B
  const int tid = threadIdx.x;
  const int l = tid & 63;
  const int wv = rfl(tid >> 6);               // 0..3
  const int r = blockIdx.x;                   // output row 0..63
  const int n = blockIdx.z;

  // zero the pad columns (posslot 0 and 65) once, both buffers/planes
  {
    uint* lp = (uint*)&lds[0][0][0];
    for (int s = tid; s < 24 * 20; s += 256) {
      const int slot = s / 20, w32 = s % 20;
      const int which = slot & 1;
      const int rowrel = (slot >> 1) % 3;
      const int plane  = ((slot >> 1) / 3) & 1;
      const int buf    = (slot >> 1) / 6;
      lp[(size_t)((buf * 2 + plane) * 198 + rowrel * 66 + (which ? 65 : 0)) * 20 + w32] = 0;
    }
  }

  const float* xn = x + ((size_t)n * CIN) * 4096;

  // staging regs: [rowrel][cc][pair]; ci = ch*32 + cc*8 + wv*2 + {0,1}
  float sreg[3][4][2];
  auto LOADG = [&](int ch) {
#pragma unroll
    for (int rr = 0; rr < 3; rr++) {
      const int ir = r - 1 + rr;
      const bool ok = (ir >= 0) && (ir < 64);
#pragma unroll
      for (int cc = 0; cc < 4; cc++) {
        const int ci0 = ch * 32 + cc * 8 + wv * 2;
        sreg[rr][cc][0] = ok ? xn[((size_t)ci0 * 64 + ir) * 64 + l] : 0.f;
        sreg[rr][cc][1] = ok ? xn[((size_t)(ci0 + 1) * 64 + ir) * 64 + l] : 0.f;
      }
    }
  };
  auto WRITE = [&](int buf) {
    uint* ph = (uint*)&lds[buf][0][0];
    uint* pl = (uint*)&lds[buf][1][0];
#pragma unroll
    for (int rr = 0; rr < 3; rr++) {
#pragma unroll
      for (int cc = 0; cc < 4; cc++) {
        float v0 = sreg[rr][cc][0], v1 = sreg[rr][cc][1];
        if (RELU_IN) { v0 = fmaxf(v0, 0.f); v1 = fmaxf(v1, 0.f); }
        const ushort h0 = f2h(v0), h1 = f2h(v1);
        const ushort m0 = f2h((v0 - h2f(h0)) * 2048.0f);
        const ushort m1 = f2h((v1 - h2f(h1)) * 2048.0f);
        const int idx = (rr * 66 + (l + 1)) * 20 + cc * 4 + wv;   // u32 index
        ph[idx] = (uint)h0 | ((uint)h1 << 16);
        pl[idx] = (uint)m0 | ((uint)m1 << 16);
      }
    }
  };

  f32x4 accH[nM], accM[nM];
#pragma unroll
  for (int m = 0; m < nM; m++) {
    const int co = m * 16 + ((l >> 4) << 2);
    accH[m] = (f32x4){bias[co], bias[co + 1], bias[co + 2], bias[co + 3]};
    accM[m] = (f32x4){0.f, 0.f, 0.f, 0.f};
  }

  const int pb = wv * 16;          // this wave's position base
  LOADG(0); WRITE(0);
  if (nCh > 1) LOADG(1);
  int cur = 0;
  for (int ch = 0; ch < nCh; ch++) {
    __syncthreads();
    const ushort* base_h = &lds[cur][0][0];
    const ushort* base_l = &lds[cur][1][0];
#pragma unroll
    for (int kh = 0; kh < 3; kh++) {
#pragma unroll
      for (int kw = 0; kw < 3; kw++) {
        const int slot = kh * 66 + pb + (l & 15) + kw;
        const h16x8 bh = *(const h16x8*)(base_h + slot * 40 + (l >> 4) * 8);
        const h16x8 bl = *(const h16x8*)(base_l + slot * 40 + (l >> 4) * 8);
        const ushort* wp = wpk + (((size_t)(kh * 3 + kw) * nCh + ch) * nM * 64 + l) * 16;
#pragma unroll
        for (int m = 0; m < nM; m++) {
          const h16x8 ah = *(const h16x8*)(wp + (size_t)m * 1024);
          const h16x8 al = *(const h16x8*)(wp + (size_t)m * 1024 + 8);
          accH[m] = __builtin_amdgcn_mfma_f32_16x16x32_f16(ah, bh, accH[m], 0, 0, 0);
          accM[m] = __builtin_amdgcn_mfma_f32_16x16x32_f16(al, bh, accM[m], 0, 0, 0);
          accM[m] = __builtin_amdgcn_mfma_f32_16x16x32_f16(ah, bl, accM[m], 0, 0, 0);
        }
      }
    }
    if (ch + 1 < nCh) {
      WRITE(cur ^ 1);
      if (ch + 2 < nCh) LOADG(ch + 2);
    }
    cur ^= 1;
  }

  const float SCL = 1.0f / 2048.0f;
  const int pos = pb + (l & 15);
  const int r4 = (l >> 4) << 2;
#pragma unroll
  for (int m = 0; m < nM; m++) {
    const int co = m * 16 + r4;
    float* yp = y + (((size_t)(n * COT + co)) * 64 + r) * 64 + pos;
#pragma unroll
    for (int j = 0; j < 4; j++)
      yp[(size_t)j * 4096] = accH[m][j] + accM[m][j] * SCL;
  }
}

// ---------------- ConvTranspose 4x4 s2 p1 via MFMA fp16x2 (up0) -----------
// Block = input row a -> output rows 2a, 2a+1 (128 wide). 4 waves x 16 b-pos.
// Same LDS geometry as conv3_mfma. 16 taps mapped on 9 (row, slot+-1) frags.
// Outputs: 0 = (2a, even), 1 = (2a, odd), 2 = (2a+1, even), 3 = (2a+1, odd).
template<int CIN, int COT, bool RELU_OUT>
__global__ __launch_bounds__(256, 2) void convt_mfma(
    const float* __restrict__ x, const ushort* __restrict__ wpk,
    const float* __restrict__ bias, float* __restrict__ y) {
  constexpr int nCh = CIN / 32, nM = COT / 16;
  __shared__ ushort lds[2][2][3 * 66 * 40];
  const int tid = threadIdx.x;
  const int l = tid & 63;
  const int wv = rfl(tid >> 6);
  const int a = blockIdx.x;                   // input row 0..63
  const int n = blockIdx.z;

  {
    uint* lp = (uint*)&lds[0][0][0];
    for (int s = tid; s < 24 * 20; s += 256) {
      const int slot = s / 20, w32 = s % 20;
      const int which = slot & 1;
      const int rowrel = (slot >> 1) % 3;
      const int plane  = ((slot >> 1) / 3) & 1;
      const int buf    = (slot >> 1) / 6;
      lp[(size_t)((buf * 2 + plane) * 198 + rowrel * 66 + (which ? 65 : 0)) * 20 + w32] = 0;
    }
  }

  const float* xn = x + ((size_t)n * CIN) * 4096;

  float sreg[3][4][2];
  auto LOADG = [&](int ch) {
#pragma unroll
    for (int rr = 0; rr < 3; rr++) {
      const int ir = a - 1 + rr;
      const bool ok = (ir >= 0) && (ir < 64);
#pragma unroll
      for (int cc = 0; cc < 4; cc++) {
        const int ci0 = ch * 32 + cc * 8 + wv * 2;
        sreg[rr][cc][0] = ok ? xn[((size_t)ci0 * 64 + ir) * 64 + l] : 0.f;
        sreg[rr][cc][1] = ok ? xn[((size_t)(ci0 + 1) * 64 + ir) * 64 + l] : 0.f;
      }
    }
  };
  auto WRITE = [&](int buf) {
    uint* ph = (uint*)&lds[buf][0][0];
    uint* pl = (uint*)&lds[buf][1][0];
#pragma unroll
    for (int rr = 0; rr < 3; rr++) {
#pragma unroll
      for (int cc = 0; cc < 4; cc++) {
        const float v0 = sreg[rr][cc][0], v1 = sreg[rr][cc][1];
        const ushort h0 = f2h(v0), h1 = f2h(v1);
        const ushort m0 = f2h((v0 - h2f(h0)) * 2048.0f);
        const ushort m1 = f2h((v1 - h2f(h1)) * 2048.0f);
        const int idx = (rr * 66 + (l + 1)) * 20 + cc * 4 + wv;
        ph[idx] = (uint)h0 | ((uint)h1 << 16);
        pl[idx] = (uint)m0 | ((uint)m1 << 16);
      }
    }
  };

  f32x4 aH[4][nM], aM[4][nM];
#pragma unroll
  for (int m = 0; m < nM; m++) {
    const int co = m * 16 + ((l >> 4) << 2);
    const f32x4 b4 = (f32x4){bias[co], bias[co + 1], bias[co + 2], bias[co + 3]};
#pragma unroll
    for (int o = 0; o < 4; o++) { aH[o][m] = b4; aM[o][m] = (f32x4){0.f,0.f,0.f,0.f}; }
  }

  const int pb = wv * 16;
  LOADG(0); WRITE(0);
  if (nCh > 1) LOADG(1);
  int cur = 0;

#define CT_APPLY(OIDX, KH, KW) {                                              \
    const ushort* wp_ = wpk + (((size_t)((KH) * 4 + (KW)) * nCh + ch) * nM * 64 + l) * 16; \
    _Pragma("unroll")                                                         \
    for (int m = 0; m < nM; m++) {                                            \
      const h16x8 ah = *(const h16x8*)(wp_ + (size_t)m * 1024);               \
      const h16x8 al = *(const h16x8*)(wp_ + (size_t)m * 1024 + 8);           \
      aH[OIDX][m] = __builtin_amdgcn_mfma_f32_16x16x32_f16(ah, bh, aH[OIDX][m], 0, 0, 0); \
      aM[OIDX][m] = __builtin_amdgcn_mfma_f32_16x16x32_f16(al, bh, aM[OIDX][m], 0, 0, 0); \
      aM[OIDX][m] = __builtin_amdgcn_mfma_f32_16x16x32_f16(ah, bl, aM[OIDX][m], 0, 0, 0); \
    }}
#define CT_FRAG(RR, DD)                                                       \
    const int slot = (RR) * 66 + pb + (l & 15) + 1 + (DD);                    \
    const h16x8 bh = *(const h16x8*)(base_h + slot * 40 + (l >> 4) * 8);      \
    const h16x8 bl = *(const h16x8*)(base_l + slot * 40 + (l >> 4) * 8);

  for (int ch = 0; ch < nCh; ch++) {
    __syncthreads();
    const ushort* base_h = &lds[cur][0][0];
    const ushort* base_l = &lds[cur][1][0];
    // rr=0 (input row a-1): kh=3 taps -> output row 2a
    { CT_FRAG(0, -1) CT_APPLY(0, 3, 3) }
    { CT_FRAG(0,  0) CT_APPLY(0, 3, 1) CT_APPLY(1, 3, 2) }
    { CT_FRAG(0, +1) CT_APPLY(1, 3, 0) }
    // rr=1 (input row a): kh=1 -> row 2a ; kh=2 -> row 2a+1
    { CT_FRAG(1, -1) CT_APPLY(0, 1, 3) CT_APPLY(2, 2, 3) }
    { CT_FRAG(1,  0) CT_APPLY(0, 1, 1) CT_APPLY(1, 1, 2) CT_APPLY(2, 2, 1) CT_APPLY(3, 2, 2) }
    { CT_FRAG(1, +1) CT_APPLY(1, 1, 0) CT_APPLY(3, 2, 0) }
    // rr=2 (input row a+1): kh=0 taps -> output row 2a+1
    { CT_FRAG(2, -1) CT_APPLY(2, 0, 3) }
    { CT_FRAG(2,  0) CT_APPLY(2, 0, 1) CT_APPLY(3, 0, 2) }
    { CT_FRAG(2, +1) CT_APPLY(3, 0, 0) }
    if (ch + 1 < nCh) {
      WRITE(cur ^ 1);
      if (ch + 2 < nCh) LOADG(ch + 2);
    }
    cur ^= 1;
  }
#undef CT_APPLY
#undef CT_FRAG

  const float SCL = 1.0f / 2048.0f;
  const int b = pb + (l & 15);
  const int oh0 = 2 * a;
  const int r4 = (l >> 4) << 2;
#pragma unroll
  for (int m = 0; m < nM; m++) {
    const int co = m * 16 + r4;
#pragma unroll
    for (int j = 0; j < 4; j++) {
      float v0e = aH[0][m][j] + aM[0][m][j] * SCL;
      float v0o = aH[1][m][j] + aM[1][m][j] * SCL;
      float v1e = aH[2][m][j] + aM[2][m][j] * SCL;
      float v1o = aH[3][m][j] + aM[3][m][j] * SCL;
      if (RELU_OUT) {
        v0e = fmaxf(v0e, 0.f); v0o = fmaxf(v0o, 0.f);
        v1e = fmaxf(v1e, 0.f); v1o = fmaxf(v1o, 0.f);
      }
      float* row0 = y + (((size_t)(n * COT + co + j)) * 128 + oh0) * 128;
      ((float2*)row0)[b] = make_float2(v0e, v0o);
      ((float2*)(row0 + 128))[b] = make_float2(v1e, v1o);
    }
  }
}

// ---------------- conv 4x4 stride2 pad1 (generic, used for conv0) ---------
template<int CIN, int COT, bool RELU_OUT, int OW>
__global__ __launch_bounds__(256) void conv4s2_row(
    const float* __restrict__ x, const float* __restrict__ w,
    const float* __restrict__ bias, float* __restrict__ y,
    int Hout, int Cout) {
  const int Win = OW * 2, Hin = Hout * 2;
  const int t = blockIdx.x * 256 + threadIdx.x;
  const int wo = t & (OW - 1);
  const int ho = rfl(t / OW);
  const int co0 = blockIdx.y * COT, n = blockIdx.z;

  float acc[COT];
#pragma unroll
  for (int u = 0; u < COT; u++) acc[u] = bias[co0 + u];

  const int iw0 = 2 * wo - 1;
  const int cA = iw0 < 0 ? 0 : iw0;
  const bool mA = iw0 >= 0;
  const int cD = (iw0 + 3 < Win) ? iw0 + 3 : Win - 1;
  const bool mD = iw0 + 3 < Win;

  for (int ci = 0; ci < CIN; ci++) {
    const float* xp = x + ((size_t)(n * CIN + ci)) * Hin * Win;
    const float* wp = w + ((size_t)(co0 * CIN + ci)) * 16;
#pragma unroll
    for (int kh = 0; kh < 4; kh++) {
      const int ih = 2 * ho - 1 + kh;
      if (ih >= 0 && ih < Hin) {
        const float* row = xp + (size_t)ih * Win;
        float x0 = row[cA];      x0 = mA ? x0 : 0.f;
        float x1 = row[iw0 + 1];
        float x2 = row[iw0 + 2];
        float x3 = row[cD];      x3 = mD ? x3 : 0.f;
#pragma unroll
        for (int u = 0; u < COT; u++) {
          const float* wr = wp + u * CIN * 16 + kh * 4;
          acc[u] = fmaf(x0, wr[0], acc[u]);
          acc[u] = fmaf(x1, wr[1], acc[u]);
          acc[u] = fmaf(x2, wr[2], acc[u]);
          acc[u] = fmaf(x3, wr[3], acc[u]);
        }
      }
    }
  }
#pragma unroll
  for (int u = 0; u < COT; u++) {
    float v = acc[u];
    if (RELU_OUT) v = fmaxf(v, 0.f);
    y[(((size_t)(n * Cout + co0 + u)) * Hout + ho) * OW + wo] = v;
  }
}

// ---------------- conv 4x4 s2 p1, 128^2 -> 64^2, async DMA, 2-img batch ---
template<int CIN, int COT, bool RELU_OUT>
__global__ __launch_bounds__(256, 4) void conv4s2_async_b2(
    const float* __restrict__ x, const float* __restrict__ w,
    const float* __restrict__ bias, float* __restrict__ y, int Cout) {
  __shared__ float xs[2][2 * 20 * 128];   // 2 x 20 KB
  const int tid = threadIdx.x;
  const int lane = tid & 63;
  const int wv = rfl(tid >> 6);           // 0..3
  const int r0 = blockIdx.x * 8;          // first output row (0..56)
  const int co0 = blockIdx.y * COT;
  const int n0 = blockIdx.z * 2;

  int gofs[5];
#pragma unroll
  for (int i = 0; i < 5; i++) {
    const int q = tid + i * 256;
    const int img = q / 640;
    const int r = q - img * 640;
    const int rr = r >> 5, f4 = r & 31;
    int grow = 2 * r0 - 2 + rr;
    grow = grow < 0 ? 0 : (grow > 127 ? 127 : grow);
    gofs[i] = img * CIN * 16384 + grow * 128 + f4 * 4;
  }
  const float* xn = x + ((size_t)(n0 * CIN)) * 16384;

  float accA[2 * COT], accB[2 * COT];
#pragma unroll
  for (int u = 0; u < COT; u++) {
    const float b = bias[co0 + u];
    accA[u] = b; accA[COT + u] = b;
    accB[u] = b; accB[COT + u] = b;
  }

  const bool mm = lane > 0;
  const bool mp = lane < 63;
  const bool invLo = (r0 == 0)  && (wv == 0);
  const bool invHi = (r0 == 56) && (wv == 3);

  {
    float* lb = &xs[0][0];
#pragma unroll
    for (int i = 0; i < 5; i++)
      async_copy16(xn + gofs[i], lb + (tid + i * 256) * 4);
  }

  int cur = 0;
  for (int ci = 0; ci < CIN; ci++) {
    __syncthreads();
    if (ci + 1 < CIN) {
      const float* xc = xn + (size_t)(ci + 1) * 16384;
      float* lb = &xs[cur ^ 1][0];
#pragma unroll
      for (int i = 0; i < 5; i++)
        async_copy16(xc + gofs[i], lb + (tid + i * 256) * 4);
    }
    const float* xb = xs[cur];
    float em[2][6], ee[2][6], oo[2][6], ep[2][6];
#pragma unroll
    for (int img = 0; img < 2; img++) {
#pragma unroll
      for (int d = 0; d < 6; d++) {
        const float* rp = xb + img * 2560 + (4 * wv + 1 + d) * 128;
        float e = rp[2 * lane];
        float o = rp[2 * lane + 1];
        float m = mm ? rp[2 * lane - 1] : 0.f;
        float p = mp ? rp[2 * lane + 2] : 0.f;
        em[img][d] = m; ee[img][d] = e; oo[img][d] = o; ep[img][d] = p;
      }
      if (invLo) { em[img][0] = 0.f; ee[img][0] = 0.f; oo[img][0] = 0.f; ep[img][0] = 0.f; }
      if (invHi) { em[img][5] = 0.f; ee[img][5] = 0.f; oo[img][5] = 0.f; ep[img][5] = 0.f; }
    }
#pragma unroll
    for (int u = 0; u < COT; u++) {
      const float* wr = w + ((size_t)((co0 + u) * CIN + ci)) * 16;  // s_load
#pragma unroll
      for (int kh = 0; kh < 4; kh++) {
        const float w0 = wr[kh * 4 + 0];
        const float w1 = wr[kh * 4 + 1];
        const float w2 = wr[kh * 4 + 2];
        const float w3 = wr[kh * 4 + 3];
#pragma unroll
        for (int img = 0; img < 2; img++) {
          const int o = img * COT + u;
          accA[o] = fmaf(em[img][kh],     w0, accA[o]);
          accA[o] = fmaf(ee[img][kh],     w1, accA[o]);
          accA[o] = fmaf(oo[img][kh],     w2, accA[o]);
          accA[o] = fmaf(ep[img][kh],     w3, accA[o]);
          accB[o] = fmaf(em[img][kh + 2], w0, accB[o]);
          accB[o] = fmaf(ee[img][kh + 2], w1, accB[o]);
          accB[o] = fmaf(oo[img][kh + 2], w2, accB[o]);
          accB[o] = fmaf(ep[img][kh + 2], w3, accB[o]);
        }
      }
    }
    cur ^= 1;
  }
  const int roA = r0 + 2 * wv;
#pragma unroll
  for (int img = 0; img < 2; img++) {
#pragma unroll
    for (int u = 0; u < COT; u++) {
      const int o = img * COT + u;
      float vA = accA[o], vB = accB[o];
      if (RELU_OUT) { vA = fmaxf(vA, 0.f); vB = fmaxf(vB, 0.f); }
      float* yp = y + (((size_t)((n0 + img) * Cout + co0 + u)) * 64 + roA) * 64 + lane;
      yp[0]  = vA;
      yp[64] = vB;
    }
  }
}

// ---------------- conv 1x1 v4: 4 positions per thread ---------------------
template<int CIN, int COT, bool RELU_IN, bool ACCUM, bool RELU_OUT>
__global__ __launch_bounds__(256) void conv1x1_v4(
    const float* __restrict__ x, const float* __restrict__ w,
    const float* __restrict__ bias, float* __restrict__ y,
    int HW, int Cout) {
  const int p = (blockIdx.x * 256 + threadIdx.x) * 4;
  const int co0 = blockIdx.y * COT, n = blockIdx.z;

  float4 acc[COT];
#pragma unroll
  for (int u = 0; u < COT; u++) {
    const float b = bias[co0 + u];
    acc[u] = make_float4(b, b, b, b);
  }
  for (int ci = 0; ci < CIN; ci++) {
    float4 xv = *(const float4*)&x[((size_t)(n * CIN + ci)) * HW + p];
    if (RELU_IN) {
      xv.x = fmaxf(xv.x, 0.f); xv.y = fmaxf(xv.y, 0.f);
      xv.z = fmaxf(xv.z, 0.f); xv.w = fmaxf(xv.w, 0.f);
    }
#pragma unroll
    for (int u = 0; u < COT; u++) {
      const float wv = w[(co0 + u) * CIN + ci];
      acc[u].x = fmaf(xv.x, wv, acc[u].x);
      acc[u].y = fmaf(xv.y, wv, acc[u].y);
      acc[u].z = fmaf(xv.z, wv, acc[u].z);
      acc[u].w = fmaf(xv.w, wv, acc[u].w);
    }
  }
#pragma unroll
  for (int u = 0; u < COT; u++) {
    float4* yp = (float4*)&y[((size_t)(n * Cout + co0 + u)) * HW + p];
    float4 r = acc[u];
    if (ACCUM) {
      float4 h = *yp;
      r.x += h.x; r.y += h.y; r.z += h.z; r.w += h.w;
    }
    if (RELU_OUT) {
      r.x = fmaxf(r.x, 0.f); r.y = fmaxf(r.y, 0.f);
      r.z = fmaxf(r.z, 0.f); r.w = fmaxf(r.w, 0.f);
    }
    *yp = r;
  }
}

// ---------------- ConvTranspose 4x4 s2 p1 (generic, used for up1) ---------
template<int CIN, int COT, bool RELU_IN, bool RELU_OUT, int WH>
__global__ __launch_bounds__(256) void convt_row(
    const float* __restrict__ x, const float* __restrict__ w,
    const float* __restrict__ bias, float* __restrict__ y,
    int Hin, int Cout) {
  const int Hout = Hin * 2;
  const int t = blockIdx.x * 256 + threadIdx.x;
  const int a = t & (WH - 1);
  const int oh = rfl(t / WH);
  const int co0 = blockIdx.y * COT, n = blockIdx.z;

  float acc0[COT], acc1[COT];
#pragma unroll
  for (int u = 0; u < COT; u++) { acc0[u] = bias[co0 + u]; acc1[u] = bias[co0 + u]; }

  const int cm = a > 0 ? a - 1 : 0;
  const bool mm = a > 0;
  const int cp = a < WH - 1 ? a + 1 : WH - 1;
  const bool mp = a < WH - 1;

  const int kh0 = (oh + 1) & 1;
#pragma unroll
  for (int dh = 0; dh < 2; dh++) {
    const int kh = kh0 + 2 * dh;
    const int ih = (oh + 1 - kh) >> 1;
    if (ih >= 0 && ih < Hin) {
      for (int ci = 0; ci < CIN; ci++) {
        const float* row = x + (((size_t)(n * CIN + ci)) * Hin + ih) * WH;
        float x0  = row[a];
        float xm1 = row[cm];  xm1 = mm ? xm1 : 0.f;
        float xp1 = row[cp];  xp1 = mp ? xp1 : 0.f;
        if (RELU_IN) {
          x0 = fmaxf(x0, 0.f); xm1 = fmaxf(xm1, 0.f); xp1 = fmaxf(xp1, 0.f);
        }
        const float* wp = w + ((size_t)(ci * Cout + co0)) * 16 + kh * 4;
#pragma unroll
        for (int u = 0; u < COT; u++) {
          const float* wr = wp + u * 16;
          acc0[u] = fmaf(x0,  wr[1], acc0[u]);
          acc0[u] = fmaf(xm1, wr[3], acc0[u]);
          acc1[u] = fmaf(xp1, wr[0], acc1[u]);
          acc1[u] = fmaf(x0,  wr[2], acc1[u]);
        }
      }
    }
  }
#pragma unroll
  for (int u = 0; u < COT; u++) {
    float v0 = acc0[u], v1 = acc1[u];
    if (RELU_OUT) { v0 = fmaxf(v0, 0.f); v1 = fmaxf(v1, 0.f); }
    float* row = y + (((size_t)(n * Cout + co0 + u)) * Hout + oh) * (2 * WH);
    ((float2*)row)[a] = make_float2(v0, v1);
  }
}

// ---------------- VQ: codebook -> fp64 (+ norms), once per call -----------
__global__ __launch_bounds__(256) void cvt_cb(
    const float* __restrict__ cb, double* __restrict__ cb64,
    double* __restrict__ cbn64) {
  const int k = blockIdx.x * 256 + threadIdx.x;   // 0..511
  double s = 0.0;
  for (int d = 0; d < 64; d++) {
    const double c = (double)cb[d * 512 + k];
    cb64[k * 64 + d] = c;
    s = fma(c, c, s);
  }
  cbn64[k] = s;
}

// ---------------- VQ v3: scalar fp64 codebook, in-place quantize ----------
__global__ __launch_bounds__(256) void vq_kernel3(
    const float* __restrict__ cb, const double* __restrict__ cb64,
    const double* __restrict__ cbn64, float* __restrict__ zq) {
  __shared__ double redD[256];
  __shared__ int    redI[256];
  __shared__ int    bestIdx[64];
  const int tid = threadIdx.x;
  const int lane = tid & 63;
  const int g = rfl(tid >> 6);
  const int n = blockIdx.x >> 6, row = blockIdx.x & 63;
  float* zp = zq + ((size_t)n) * 262144 + (row << 6) + lane;

  double zr[64];
#pragma unroll
  for (int d = 0; d < 64; d++) zr[d] = (double)zp[(size_t)d * 4096];

  int best = 0;
  double bestd = 1e300;
  const double* cbk = cb64 + (size_t)g * 128 * 64;
  for (int j = 0; j < 128; j++) {
    const double* cw = cbk + j * 64;      // wave-uniform -> s_load
    double d0 = 0.0, d1 = 0.0, d2 = 0.0, d3 = 0.0;
#pragma unroll
    for (int d = 0; d < 64; d += 4) {
      d0 = fma(zr[d],     cw[d],     d0);
      d1 = fma(zr[d + 1], cw[d + 1], d1);
      d2 = fma(zr[d + 2], cw[d + 2], d2);
      d3 = fma(zr[d + 3], cw[d + 3], d3);
    }
    const int k = g * 128 + j;
    const double dist = cbn64[k] - 2.0 * ((d0 + d1) + (d2 + d3));
    if (dist < bestd) { bestd = dist; best = k; }
  }
  redD[tid] = bestd;
  redI[tid] = best;
  __syncthreads();
  if (tid < 64) {
    double bd = redD[lane];
    int bi = redI[lane];
#pragma unroll
    for (int gg = 1; gg < 4; gg++) {
      const double dd = redD[gg * 64 + lane];
      const int ii = redI[gg * 64 + lane];
      if (dd < bd || (dd == bd && ii < bi)) { bd = dd; bi = ii; }
    }
    bestIdx[lane] = bi;
  }
  __syncthreads();
  const int k = bestIdx[lane];
#pragma unroll
  for (int j = 0; j < 16; j++) {
    const int d = g * 16 + j;
    zp[(size_t)d * 4096] = cb[d * 512 + k];
  }
}

// -------------------------------------------------------------------------
extern "C" void kernel_launch(void* const* d_in, const int* in_sizes, int n_in,
                              void* d_out, int out_size, void* d_ws, size_t ws_size,
                              hipStream_t stream) {
  const float* x          = (const float*)d_in[0];
  const float* enc_w0     = (const float*)d_in[1];
  const float* enc_b0     = (const float*)d_in[2];
  const float* enc_w1     = (const float*)d_in[3];
  const float* enc_b1     = (const float*)d_in[4];
  const float* enc_wf     = (const float*)d_in[5];
  const float* enc_bf     = (const float*)d_in[6];
  const float* enc_res_w1 = (const float*)d_in[7];
  const float* enc_res_b1 = (const float*)d_in[8];
  const float* enc_res_w2 = (const float*)d_in[9];
  const float* enc_res_b2 = (const float*)d_in[10];
  const float* pre_w      = (const float*)d_in[11];
  const float* pre_b      = (const float*)d_in[12];
  const float* codebook   = (const float*)d_in[13];
  const float* dec_w      = (const float*)d_in[14];
  const float* dec_b      = (const float*)d_in[15];
  const float* dec_res_w1 = (const float*)d_in[16];
  const float* dec_res_b1 = (const float*)d_in[17];
  const float* dec_res_w2 = (const float*)d_in[18];
  const float* dec_res_b2 = (const float*)d_in[19];
  const float* up_w0      = (const float*)d_in[20];
  const float* up_b0      = (const float*)d_in[21];
  const float* up_w1      = (const float*)d_in[22];
  const float* up_b1      = (const float*)d_in[23];
  float* out = (float*)d_out;

  float* A = (float*)d_ws;         // 16,777,216 floats (64 MB)
  float* B = A + 16777216;         //  8,388,608 floats (32 MB)
  float* C = B + 8388608;          //  8,388,608 floats (32 MB)
  double* cb64  = (double*)(A + 6291456);          // 256 KB, VQ window only
  double* cbn64 = (double*)(A + 6291456 + 65536);  // 4 KB
  // conv3 weight packs in A's tail (floats 8.39M..). LIVENESS: written
  // after conv1 (A dead then); later A writers stay below 4.2M floats
  // (res h1 2.1M, z 4.19M, cb64 6.29M..6.36M); dead before up0 rewrites A.
  ushort* wpkF  = (ushort*)(A + 8388608);          // convf  294912 ush
  ushort* wpkEa = wpkF  + 294912;                  // enc r1a 73728
  ushort* wpkEb = wpkEa + 73728;                   // enc r1b 73728
  ushort* wpkD  = wpkEb + 73728;                   // dec    147456
  ushort* wpkDa = wpkD  + 147456;                  // dec r1a 73728
  ushort* wpkDb = wpkDa + 73728;                   // dec r1b 73728
  // up0 pack in C (C dead after pre; nothing else writes C afterwards)
  ushort* wpkT  = (ushort*)C;                      // 262144 ush

  const dim3 blk(256);
  const int N = 16;

  // --- Encoder ---
  conv4s2_row<3, 16, true, 128><<<dim3(64, 4, N), blk, 0, stream>>>(
      x, enc_w0, enc_b0, A, 128, 64);
  conv4s2_async_b2<64, 4, true><<<dim3(8, 32, N / 2), blk, 0, stream>>>(
      A, enc_w1, enc_b1, B, 128);

  // --- conv3 weight prepacks into A's tail (A dead: conv1 consumed it) ---
  prep_w3<128, 128><<<dim3(72), blk, 0, stream>>>(enc_wf, wpkF);
  prep_w3<128, 32><<<dim3(18), blk, 0, stream>>>(enc_res_w1, wpkEa);
  prep_w3<128, 32><<<dim3(18), blk, 0, stream>>>(
      enc_res_w1 + (size_t)32 * 128 * 9, wpkEb);
  prep_w3<64, 128><<<dim3(36), blk, 0, stream>>>(dec_w, wpkD);
  prep_w3<128, 32><<<dim3(18), blk, 0, stream>>>(dec_res_w1, wpkDa);
  prep_w3<128, 32><<<dim3(18), blk, 0, stream>>>(
      dec_res_w1 + (size_t)32 * 128 * 9, wpkDb);

  // convf: MFMA (input B already relu'd)
  conv3_mfma<128, 128, false><<<dim3(64, 1, N), blk, 0, stream>>>(
      B, wpkF, enc_bf, C);
  // enc res stack on C
  conv3_mfma<128, 32, true><<<dim3(64, 1, N), blk, 0, stream>>>(
      C, wpkEa, enc_res_b1, A);
  conv1x1_v4<32, 8, true, true, false><<<dim3(4, 16, N), blk, 0, stream>>>(
      A, enc_res_w2, enc_res_b2, C, 4096, 128);
  conv3_mfma<128, 32, true><<<dim3(64, 1, N), blk, 0, stream>>>(
      C, wpkEb, enc_res_b1 + 32, A);
  conv1x1_v4<32, 8, true, true, true><<<dim3(4, 16, N), blk, 0, stream>>>(
      A, enc_res_w2 + (size_t)128 * 32, enc_res_b2 + 128, C, 4096, 128);
  // pre: C already relu'd -> z in A
  conv1x1_v4<128, 8, false, false, false><<<dim3(4, 8, N), blk, 0, stream>>>(
      C, pre_w, pre_b, A, 4096, 64);

  // --- up0 weight prepack into C (C dead after pre) ---
  prep_wt<128, 64><<<dim3(64), blk, 0, stream>>>(up_w0, wpkT);

  // --- VQ (in-place on A; cb64 written here, after z, before use) ---
  cvt_cb<<<dim3(2), blk, 0, stream>>>(codebook, cb64, cbn64);
  vq_kernel3<<<dim3(1024), blk, 0, stream>>>(codebook, cb64, cbn64, A);

  // --- Decoder ---
  conv3_mfma<64, 128, false><<<dim3(64, 1, N), blk, 0, stream>>>(
      A, wpkD, dec_b, B);
  conv3_mfma<128, 32, true><<<dim3(64, 1, N), blk, 0, stream>>>(
      B, wpkDa, dec_res_b1, A);
  conv1x1_v4<32, 8, true, true, false><<<dim3(4, 16, N), blk, 0, stream>>>(
      A, dec_res_w2, dec_res_b2, B, 4096, 128);
  conv3_mfma<128, 32, true><<<dim3(64, 1, N), blk, 0, stream>>>(
      B, wpkDb, dec_res_b1 + 32, A);
  conv1x1_v4<32, 8, true, true, true><<<dim3(4, 16, N), blk, 0, stream>>>(
      A, dec_res_w2 + (size_t)128 * 32, dec_res_b2 + 128, B, 4096, 128);
  // up0: MFMA ConvTranspose, B (relu'd) -> A(16,64,128,128), ReLU out
  convt_mfma<128, 64, true><<<dim3(64, 1, N), blk, 0, stream>>>(
      B, wpkT, up_b0, A);
  // up1: A -> out(16,3,256,256)
  convt_row<64, 3, false, false, 128><<<dim3(128, 1, N), blk, 0, stream>>>(
      A, up_w1, up_b1, out, 128, 3);
}

// Round 4
// 1132.430 us; speedup vs baseline: 1.8633x; 1.0606x over previous
//
#include <hip/hip_runtime.h>
#include <math.h>

// -------------------------------------------------------------------------
// VQ-VAE forward, fp32, round 25: conv1 (4x4 s2, 64->128) moved to MFMA.
//  - conv4s2_mfma: stride-2 conv as implicit GEMM. Input cols split
//    even/odd -> the 4 kw taps become +-1 slot reads (conv3 geometry):
//    iw=2wo-1+kw -> odd[wo-1], even[wo], odd[wo], even[wo+1].
//    kh split into 2 stage-steps (rows 2ho-1,2ho | 2ho+1,2ho+2); single
//    LDS buffer (42.2 KB) + register prefetch (async-stage): LOADG(next)
//    issued between barriers, HBM latency hides under 192-MFMA phase.
//  - Weight pack wpk1 in C's head: C dead until convf; conv1 is the only
//    reader and runs before convf. prep_w4 launched first (writes C only).
//  - Everything else identical to R24 (1201 us, absmax 9.77e-4).
// Remaining fp32 VALU: conv0, 1x1s, up1, VQ(fp64).
// -------------------------------------------------------------------------

#define DEV __device__ __forceinline__

DEV int rfl(int v) { return __builtin_amdgcn_readfirstlane(v); }

DEV void async_copy16(const float* g, float* l) {
  __builtin_amdgcn_global_load_lds(
      (const __attribute__((address_space(1))) void*)g,
      (__attribute__((address_space(3))) void*)l, 16, 0, 0);
}

typedef __attribute__((ext_vector_type(8))) _Float16 h16x8;
typedef __attribute__((ext_vector_type(4))) float f32x4;

DEV ushort f2h(float f) {
  _Float16 h = (_Float16)f;
  return __builtin_bit_cast(ushort, h);
}
DEV float h2f(ushort u) { return (float)__builtin_bit_cast(_Float16, u); }
DEV uint pk(ushort a, ushort b) { return (uint)a | ((uint)b << 16); }

// ---------------- weight prepack for conv3_mfma ---------------------------
// Layout: [khkw 9][ch CIN/32][m COT/16][lane 64][hi8 | lo8] f16 (lo*2^11).
template<int CIN, int COT>
__global__ __launch_bounds__(256) void prep_w3(
    const float* __restrict__ w, ushort* __restrict__ wpk) {
  constexpr int nCh = CIN / 32, nM = COT / 16;
  const int t = blockIdx.x * 256 + threadIdx.x;
  if (t >= 9 * nCh * nM * 64) return;
  const int l = t & 63;
  int q = t >> 6;
  const int m = q % nM;  q /= nM;
  const int ch = q % nCh; q /= nCh;
  const int khkw = q;
  const int co = m * 16 + (l & 15);
  const int k8 = (l >> 4) * 8;
  ushort* o = wpk + (size_t)t * 16;
#pragma unroll
  for (int i = 0; i < 8; i++) {
    const int ci = ch * 32 + k8 + i;
    const float v = w[((size_t)co * CIN + ci) * 9 + khkw];
    const ushort hi = f2h(v);
    o[i]     = hi;
    o[8 + i] = f2h((v - h2f(hi)) * 2048.0f);
  }
}

// ---------------- weight prepack for conv4s2_mfma (4x4 OIHW) --------------
// Layout: [tap kh*4+kw 16][ch CIN/32][m COT/16][lane 64][hi8 | lo8].
template<int CIN, int COT>
__global__ __launch_bounds__(256) void prep_w4(
    const float* __restrict__ w, ushort* __restrict__ wpk) {
  constexpr int nCh = CIN / 32, nM = COT / 16;
  const int t = blockIdx.x * 256 + threadIdx.x;
  if (t >= 16 * nCh * nM * 64) return;
  const int l = t & 63;
  int q = t >> 6;
  const int m = q % nM;  q /= nM;
  const int ch = q % nCh; q /= nCh;
  const int tap = q;
  const int co = m * 16 + (l & 15);
  const int k8 = (l >> 4) * 8;
  ushort* o = wpk + (size_t)t * 16;
#pragma unroll
  for (int i = 0; i < 8; i++) {
    const int ci = ch * 32 + k8 + i;
    const float v = w[((size_t)co * CIN + ci) * 16 + tap];
    const ushort hi = f2h(v);
    o[i]     = hi;
    o[8 + i] = f2h((v - h2f(hi)) * 2048.0f);
  }
}

// ---------------- weight prepack for convt_mfma (4x4, w[ci][co][kh][kw]) --
template<int CIN, int COT>
__global__ __launch_bounds__(256) void prep_wt(
    const float* __restrict__ w, ushort* __restrict__ wpk) {
  constexpr int nCh = CIN / 32, nM = COT / 16;
  const int t = blockIdx.x * 256 + threadIdx.x;
  if (t >= 16 * nCh * nM * 64) return;
  const int l = t & 63;
  int q = t >> 6;
  const int m = q % nM;  q /= nM;
  const int ch = q % nCh; q /= nCh;
  const int kh = q >> 2, kw = q & 3;
  const int co = m * 16 + (l & 15);
  const int k8 = (l >> 4) * 8;
  ushort* o = wpk + (size_t)t * 16;
#pragma unroll
  for (int i = 0; i < 8; i++) {
    const int ci = ch * 32 + k8 + i;
    const float v = w[(((size_t)ci * COT + co) * 4 + kh) * 4 + kw];
    const ushort hi = f2h(v);
    o[i]     = hi;
    o[8 + i] = f2h((v - h2f(hi)) * 2048.0f);
  }
}

// ---------------- conv 4x4 s2 p1 via MFMA fp16x2 (128^2 -> 64^2) ----------
// Block = 1 output row ho x all COT. 4 waves x 16 positions.
// Even/odd col split: taps kw=0..3 -> (odd,+0)(even,+1)(odd,+1)(even,+2).
// kh split in 2 stage-steps: rows 2ho-1,2ho (kh 0,1) | 2ho+1,2ho+2 (kh 2,3).
// LDS single-buffer [prec 2][rr 2][eo 2][slot 66][40 ush] = 42.2 KB;
// register prefetch hides HBM latency under the MFMA phase.
template<int CIN, int COT, bool RELU_OUT>
__global__ __launch_bounds__(256, 2) void conv4s2_mfma(
    const float* __restrict__ x, const ushort* __restrict__ wpk,
    const float* __restrict__ bias, float* __restrict__ y) {
  constexpr int nCh = CIN / 32, nM = COT / 16;
  constexpr int nStep = nCh * 2;
  __shared__ ushort lds[2][2][2][66][40];
  const int tid = threadIdx.x;
  const int l = tid & 63;
  const int wv = rfl(tid >> 6);
  const int ho = blockIdx.x;                  // output row 0..63
  const int n = blockIdx.z;

  // zero pad slots 0 and 65 in all 8 plane-combos
  {
    uint* lp = (uint*)&lds[0][0][0][0][0];
    for (int s = tid; s < 16 * 20; s += 256) {
      const int c = s / 20, w32 = s % 20;
      const int which = c & 1, rest = c >> 1;     // rest = prec*4+rr*2+eo
      lp[(size_t)(rest * 66 + (which ? 65 : 0)) * 20 + w32] = 0;
    }
  }

  const float* xn = x + ((size_t)n * CIN) * 16384;

  // sreg[rr][cc][p]: float2 (even=.x @ col 2l, odd=.y @ col 2l+1),
  // ci = ch*32 + cc*8 + wv*2 + p
  float2 sreg[2][4][2];
  auto LOADG = [&](int step) {
    const int ch = step >> 1, h = step & 1;
#pragma unroll
    for (int rr = 0; rr < 2; rr++) {
      const int ir = 2 * ho - 1 + 2 * h + rr;
      const bool ok = (ir >= 0) && (ir < 128);
      const int irc = ok ? ir : 0;
#pragma unroll
      for (int cc = 0; cc < 4; cc++) {
        const int ci0 = ch * 32 + cc * 8 + wv * 2;
        float2 a = *(const float2*)(xn + (size_t)ci0 * 16384 + irc * 128 + 2 * l);
        float2 b = *(const float2*)(xn + (size_t)(ci0 + 1) * 16384 + irc * 128 + 2 * l);
        if (!ok) { a = make_float2(0.f, 0.f); b = make_float2(0.f, 0.f); }
        sreg[rr][cc][0] = a;
        sreg[rr][cc][1] = b;
      }
    }
  };
  auto WRITE = [&]() {
    uint* base = (uint*)&lds[0][0][0][0][0];
#pragma unroll
    for (int rr = 0; rr < 2; rr++) {
#pragma unroll
      for (int cc = 0; cc < 4; cc++) {
        const float e0 = sreg[rr][cc][0].x, o0 = sreg[rr][cc][0].y;
        const float e1 = sreg[rr][cc][1].x, o1 = sreg[rr][cc][1].y;
        const ushort he0 = f2h(e0), ho_0 = f2h(o0);
        const ushort he1 = f2h(e1), ho_1 = f2h(o1);
        const ushort le0 = f2h((e0 - h2f(he0)) * 2048.0f);
        const ushort lo0 = f2h((o0 - h2f(ho_0)) * 2048.0f);
        const ushort le1 = f2h((e1 - h2f(he1)) * 2048.0f);
        const ushort lo1 = f2h((o1 - h2f(ho_1)) * 2048.0f);
        const int u = cc * 4 + wv;
        const size_t sl20 = (size_t)(l + 1) * 20 + u;
        base[(size_t)((0 * 2 + rr) * 2 + 0) * 1320 + sl20] = pk(he0, he1);
        base[(size_t)((0 * 2 + rr) * 2 + 1) * 1320 + sl20] = pk(ho_0, ho_1);
        base[(size_t)((1 * 2 + rr) * 2 + 0) * 1320 + sl20] = pk(le0, le1);
        base[(size_t)((1 * 2 + rr) * 2 + 1) * 1320 + sl20] = pk(lo0, lo1);
      }
    }
  };

  f32x4 accH[nM], accM[nM];
#pragma unroll
  for (int m = 0; m < nM; m++) {
    const int co = m * 16 + ((l >> 4) << 2);
    accH[m] = (f32x4){bias[co], bias[co + 1], bias[co + 2], bias[co + 3]};
    accM[m] = (f32x4){0.f, 0.f, 0.f, 0.f};
  }

  const int pb = wv * 16;
  LOADG(0);
  for (int step = 0; step < nStep; step++) {
    __syncthreads();                 // previous MFMA reads done
    WRITE();
    if (step + 1 < nStep) LOADG(step + 1);   // in-flight during MFMA
    __syncthreads();                 // staged data visible
    const int ch = step >> 1, h = step & 1;
#pragma unroll
    for (int rr = 0; rr < 2; rr++) {
      const int kh = 2 * h + rr;
#pragma unroll
      for (int kw = 0; kw < 4; kw++) {
        const int eo = (kw == 0 || kw == 2) ? 1 : 0;
        const int sh = (kw == 0) ? 0 : (kw == 3) ? 2 : 1;
        const int sl = pb + (l & 15) + sh;
        const h16x8 bh = *(const h16x8*)(&lds[0][rr][eo][sl][(l >> 4) * 8]);
        const h16x8 bl = *(const h16x8*)(&lds[1][rr][eo][sl][(l >> 4) * 8]);
        const ushort* wp = wpk + (((size_t)(kh * 4 + kw) * nCh + ch) * nM * 64 + l) * 16;
#pragma unroll
        for (int m = 0; m < nM; m++) {
          const h16x8 ah = *(const h16x8*)(wp + (size_t)m * 1024);
          const h16x8 al = *(const h16x8*)(wp + (size_t)m * 1024 + 8);
          accH[m] = __builtin_amdgcn_mfma_f32_16x16x32_f16(ah, bh, accH[m], 0, 0, 0);
          accM[m] = __builtin_amdgcn_mfma_f32_16x16x32_f16(al, bh, accM[m], 0, 0, 0);
          accM[m] = __builtin_amdgcn_mfma_f32_16x16x32_f16(ah, bl, accM[m], 0, 0, 0);
        }
      }
    }
  }

  const float SCL = 1.0f / 2048.0f;
  const int pos = pb + (l & 15);
  const int r4 = (l >> 4) << 2;
#pragma unroll
  for (int m = 0; m < nM; m++) {
    const int co = m * 16 + r4;
    float* yp = y + (((size_t)(n * COT + co)) * 64 + ho) * 64 + pos;
#pragma unroll
    for (int j = 0; j < 4; j++) {
      float v = accH[m][j] + accM[m][j] * SCL;
      if (RELU_OUT) v = fmaxf(v, 0.f);
      yp[(size_t)j * 4096] = v;
    }
  }
}

// ---------------- conv 3x3 s1 p1 via MFMA fp16x2 (64x64 imgs) -------------
template<int CIN, int COT, bool RELU_IN>
__global__ __launch_bounds__(256, 2) void conv3_mfma(
    const float* __restrict__ x, const ushort* __restrict__ wpk,
    const float* __restrict__ bias, float* __restrict__ y) {
  constexpr int nCh = CIN / 32, nM = COT / 16;
  __shared__ ushort lds[2][2][3 * 66 * 40];   // 63,360 B
  const int tid = threadIdx.x;
  const int l = tid & 63;
  const int wv = rfl(tid >> 6);               // 0..3
  const int r = blockIdx.x;                   // output row 0..63
  const int n = blockIdx.z;

  {
    uint* lp = (uint*)&lds[0][0][0];
    for (int s = tid; s < 24 * 20; s += 256) {
      const int slot = s / 20, w32 = s % 20;
      const int which = slot & 1;
      const int rowrel = (slot >> 1) % 3;
      const int plane  = ((slot >> 1) / 3) & 1;
      const int buf    = (slot >> 1) / 6;
      lp[(size_t)((buf * 2 + plane) * 198 + rowrel * 66 + (which ? 65 : 0)) * 20 + w32] = 0;
    }
  }

  const float* xn = x + ((size_t)n * CIN) * 4096;

  float sreg[3][4][2];
  auto LOADG = [&](int ch) {
#pragma unroll
    for (int rr = 0; rr < 3; rr++) {
      const int ir = r - 1 + rr;
      const bool ok = (ir >= 0) && (ir < 64);
#pragma unroll
      for (int cc = 0; cc < 4; cc++) {
        const int ci0 = ch * 32 + cc * 8 + wv * 2;
        sreg[rr][cc][0] = ok ? xn[((size_t)ci0 * 64 + ir) * 64 + l] : 0.f;
        sreg[rr][cc][1] = ok ? xn[((size_t)(ci0 + 1) * 64 + ir) * 64 + l] : 0.f;
      }
    }
  };
  auto WRITE = [&](int buf) {
    uint* ph = (uint*)&lds[buf][0][0];
    uint* pl = (uint*)&lds[buf][1][0];
#pragma unroll
    for (int rr = 0; rr < 3; rr++) {
#pragma unroll
      for (int cc = 0; cc < 4; cc++) {
        float v0 = sreg[rr][cc][0], v1 = sreg[rr][cc][1];
        if (RELU_IN) { v0 = fmaxf(v0, 0.f); v1 = fmaxf(v1, 0.f); }
        const ushort h0 = f2h(v0), h1 = f2h(v1);
        const ushort m0 = f2h((v0 - h2f(h0)) * 2048.0f);
        const ushort m1 = f2h((v1 - h2f(h1)) * 2048.0f);
        const int idx = (rr * 66 + (l + 1)) * 20 + cc * 4 + wv;   // u32 index
        ph[idx] = (uint)h0 | ((uint)h1 << 16);
        pl[idx] = (uint)m0 | ((uint)m1 << 16);
      }
    }
  };

  f32x4 accH[nM], accM[nM];
#pragma unroll
  for (int m = 0; m < nM; m++) {
    const int co = m * 16 + ((l >> 4) << 2);
    accH[m] = (f32x4){bias[co], bias[co + 1], bias[co + 2], bias[co + 3]};
    accM[m] = (f32x4){0.f, 0.f, 0.f, 0.f};
  }

  const int pb = wv * 16;          // this wave's position base
  LOADG(0); WRITE(0);
  if (nCh > 1) LOADG(1);
  int cur = 0;
  for (int ch = 0; ch < nCh; ch++) {
    __syncthreads();
    const ushort* base_h = &lds[cur][0][0];
    const ushort* base_l = &lds[cur][1][0];
#pragma unroll
    for (int kh = 0; kh < 3; kh++) {
#pragma unroll
      for (int kw = 0; kw < 3; kw++) {
        const int slot = kh * 66 + pb + (l & 15) + kw;
        const h16x8 bh = *(const h16x8*)(base_h + slot * 40 + (l >> 4) * 8);
        const h16x8 bl = *(const h16x8*)(base_l + slot * 40 + (l >> 4) * 8);
        const ushort* wp = wpk + (((size_t)(kh * 3 + kw) * nCh + ch) * nM * 64 + l) * 16;
#pragma unroll
        for (int m = 0; m < nM; m++) {
          const h16x8 ah = *(const h16x8*)(wp + (size_t)m * 1024);
          const h16x8 al = *(const h16x8*)(wp + (size_t)m * 1024 + 8);
          accH[m] = __builtin_amdgcn_mfma_f32_16x16x32_f16(ah, bh, accH[m], 0, 0, 0);
          accM[m] = __builtin_amdgcn_mfma_f32_16x16x32_f16(al, bh, accM[m], 0, 0, 0);
          accM[m] = __builtin_amdgcn_mfma_f32_16x16x32_f16(ah, bl, accM[m], 0, 0, 0);
        }
      }
    }
    if (ch + 1 < nCh) {
      WRITE(cur ^ 1);
      if (ch + 2 < nCh) LOADG(ch + 2);
    }
    cur ^= 1;
  }

  const float SCL = 1.0f / 2048.0f;
  const int pos = pb + (l & 15);
  const int r4 = (l >> 4) << 2;
#pragma unroll
  for (int m = 0; m < nM; m++) {
    const int co = m * 16 + r4;
    float* yp = y + (((size_t)(n * COT + co)) * 64 + r) * 64 + pos;
#pragma unroll
    for (int j = 0; j < 4; j++)
      yp[(size_t)j * 4096] = accH[m][j] + accM[m][j] * SCL;
  }
}

// ---------------- ConvTranspose 4x4 s2 p1 via MFMA fp16x2 (up0) -----------
template<int CIN, int COT, bool RELU_OUT>
__global__ __launch_bounds__(256, 2) void convt_mfma(
    const float* __restrict__ x, const ushort* __restrict__ wpk,
    const float* __restrict__ bias, float* __restrict__ y) {
  constexpr int nCh = CIN / 32, nM = COT / 16;
  __shared__ ushort lds[2][2][3 * 66 * 40];
  const int tid = threadIdx.x;
  const int l = tid & 63;
  const int wv = rfl(tid >> 6);
  const int a = blockIdx.x;                   // input row 0..63
  const int n = blockIdx.z;

  {
    uint* lp = (uint*)&lds[0][0][0];
    for (int s = tid; s < 24 * 20; s += 256) {
      const int slot = s / 20, w32 = s % 20;
      const int which = slot & 1;
      const int rowrel = (slot >> 1) % 3;
      const int plane  = ((slot >> 1) / 3) & 1;
      const int buf    = (slot >> 1) / 6;
      lp[(size_t)((buf * 2 + plane) * 198 + rowrel * 66 + (which ? 65 : 0)) * 20 + w32] = 0;
    }
  }

  const float* xn = x + ((size_t)n * CIN) * 4096;

  float sreg[3][4][2];
  auto LOADG = [&](int ch) {
#pragma unroll
    for (int rr = 0; rr < 3; rr++) {
      const int ir = a - 1 + rr;
      const bool ok = (ir >= 0) && (ir < 64);
#pragma unroll
      for (int cc = 0; cc < 4; cc++) {
        const int ci0 = ch * 32 + cc * 8 + wv * 2;
        sreg[rr][cc][0] = ok ? xn[((size_t)ci0 * 64 + ir) * 64 + l] : 0.f;
        sreg[rr][cc][1] = ok ? xn[((size_t)(ci0 + 1) * 64 + ir) * 64 + l] : 0.f;
      }
    }
  };
  auto WRITE = [&](int buf) {
    uint* ph = (uint*)&lds[buf][0][0];
    uint* pl = (uint*)&lds[buf][1][0];
#pragma unroll
    for (int rr = 0; rr < 3; rr++) {
#pragma unroll
      for (int cc = 0; cc < 4; cc++) {
        const float v0 = sreg[rr][cc][0], v1 = sreg[rr][cc][1];
        const ushort h0 = f2h(v0), h1 = f2h(v1);
        const ushort m0 = f2h((v0 - h2f(h0)) * 2048.0f);
        const ushort m1 = f2h((v1 - h2f(h1)) * 2048.0f);
        const int idx = (rr * 66 + (l + 1)) * 20 + cc * 4 + wv;
        ph[idx] = (uint)h0 | ((uint)h1 << 16);
        pl[idx] = (uint)m0 | ((uint)m1 << 16);
      }
    }
  };

  f32x4 aH[4][nM], aM[4][nM];
#pragma unroll
  for (int m = 0; m < nM; m++) {
    const int co = m * 16 + ((l >> 4) << 2);
    const f32x4 b4 = (f32x4){bias[co], bias[co + 1], bias[co + 2], bias[co + 3]};
#pragma unroll
    for (int o = 0; o < 4; o++) { aH[o][m] = b4; aM[o][m] = (f32x4){0.f,0.f,0.f,0.f}; }
  }

  const int pb = wv * 16;
  LOADG(0); WRITE(0);
  if (nCh > 1) LOADG(1);
  int cur = 0;

#define CT_APPLY(OIDX, KH, KW) {                                              \
    const ushort* wp_ = wpk + (((size_t)((KH) * 4 + (KW)) * nCh + ch) * nM * 64 + l) * 16; \
    _Pragma("unroll")                                                         \
    for (int m = 0; m < nM; m++) {                                            \
      const h16x8 ah = *(const h16x8*)(wp_ + (size_t)m * 1024);               \
      const h16x8 al = *(const h16x8*)(wp_ + (size_t)m * 1024 + 8);           \
      aH[OIDX][m] = __builtin_amdgcn_mfma_f32_16x16x32_f16(ah, bh, aH[OIDX][m], 0, 0, 0); \
      aM[OIDX][m] = __builtin_amdgcn_mfma_f32_16x16x32_f16(al, bh, aM[OIDX][m], 0, 0, 0); \
      aM[OIDX][m] = __builtin_amdgcn_mfma_f32_16x16x32_f16(ah, bl, aM[OIDX][m], 0, 0, 0); \
    }}
#define CT_FRAG(RR, DD)                                                       \
    const int slot = (RR) * 66 + pb + (l & 15) + 1 + (DD);                    \
    const h16x8 bh = *(const h16x8*)(base_h + slot * 40 + (l >> 4) * 8);      \
    const h16x8 bl = *(const h16x8*)(base_l + slot * 40 + (l >> 4) * 8);

  for (int ch = 0; ch < nCh; ch++) {
    __syncthreads();
    const ushort* base_h = &lds[cur][0][0];
    const ushort* base_l = &lds[cur][1][0];
    { CT_FRAG(0, -1) CT_APPLY(0, 3, 3) }
    { CT_FRAG(0,  0) CT_APPLY(0, 3, 1) CT_APPLY(1, 3, 2) }
    { CT_FRAG(0, +1) CT_APPLY(1, 3, 0) }
    { CT_FRAG(1, -1) CT_APPLY(0, 1, 3) CT_APPLY(2, 2, 3) }
    { CT_FRAG(1,  0) CT_APPLY(0, 1, 1) CT_APPLY(1, 1, 2) CT_APPLY(2, 2, 1) CT_APPLY(3, 2, 2) }
    { CT_FRAG(1, +1) CT_APPLY(1, 1, 0) CT_APPLY(3, 2, 0) }
    { CT_FRAG(2, -1) CT_APPLY(2, 0, 3) }
    { CT_FRAG(2,  0) CT_APPLY(2, 0, 1) CT_APPLY(3, 0, 2) }
    { CT_FRAG(2, +1) CT_APPLY(3, 0, 0) }
    if (ch + 1 < nCh) {
      WRITE(cur ^ 1);
      if (ch + 2 < nCh) LOADG(ch + 2);
    }
    cur ^= 1;
  }
#undef CT_APPLY
#undef CT_FRAG

  const float SCL = 1.0f / 2048.0f;
  const int b = pb + (l & 15);
  const int oh0 = 2 * a;
  const int r4 = (l >> 4) << 2;
#pragma unroll
  for (int m = 0; m < nM; m++) {
    const int co = m * 16 + r4;
#pragma unroll
    for (int j = 0; j < 4; j++) {
      float v0e = aH[0][m][j] + aM[0][m][j] * SCL;
      float v0o = aH[1][m][j] + aM[1][m][j] * SCL;
      float v1e = aH[2][m][j] + aM[2][m][j] * SCL;
      float v1o = aH[3][m][j] + aM[3][m][j] * SCL;
      if (RELU_OUT) {
        v0e = fmaxf(v0e, 0.f); v0o = fmaxf(v0o, 0.f);
        v1e = fmaxf(v1e, 0.f); v1o = fmaxf(v1o, 0.f);
      }
      float* row0 = y + (((size_t)(n * COT + co + j)) * 128 + oh0) * 128;
      ((float2*)row0)[b] = make_float2(v0e, v0o);
      ((float2*)(row0 + 128))[b] = make_float2(v1e, v1o);
    }
  }
}

// ---------------- conv 4x4 stride2 pad1 (generic, used for conv0) ---------
template<int CIN, int COT, bool RELU_OUT, int OW>
__global__ __launch_bounds__(256) void conv4s2_row(
    const float* __restrict__ x, const float* __restrict__ w,
    const float* __restrict__ bias, float* __restrict__ y,
    int Hout, int Cout) {
  const int Win = OW * 2, Hin = Hout * 2;
  const int t = blockIdx.x * 256 + threadIdx.x;
  const int wo = t & (OW - 1);
  const int ho = rfl(t / OW);
  const int co0 = blockIdx.y * COT, n = blockIdx.z;

  float acc[COT];
#pragma unroll
  for (int u = 0; u < COT; u++) acc[u] = bias[co0 + u];

  const int iw0 = 2 * wo - 1;
  const int cA = iw0 < 0 ? 0 : iw0;
  const bool mA = iw0 >= 0;
  const int cD = (iw0 + 3 < Win) ? iw0 + 3 : Win - 1;
  const bool mD = iw0 + 3 < Win;

  for (int ci = 0; ci < CIN; ci++) {
    const float* xp = x + ((size_t)(n * CIN + ci)) * Hin * Win;
    const float* wp = w + ((size_t)(co0 * CIN + ci)) * 16;
#pragma unroll
    for (int kh = 0; kh < 4; kh++) {
      const int ih = 2 * ho - 1 + kh;
      if (ih >= 0 && ih < Hin) {
        const float* row = xp + (size_t)ih * Win;
        float x0 = row[cA];      x0 = mA ? x0 : 0.f;
        float x1 = row[iw0 + 1];
        float x2 = row[iw0 + 2];
        float x3 = row[cD];      x3 = mD ? x3 : 0.f;
#pragma unroll
        for (int u = 0; u < COT; u++) {
          const float* wr = wp + u * CIN * 16 + kh * 4;
          acc[u] = fmaf(x0, wr[0], acc[u]);
          acc[u] = fmaf(x1, wr[1], acc[u]);
          acc[u] = fmaf(x2, wr[2], acc[u]);
          acc[u] = fmaf(x3, wr[3], acc[u]);
        }
      }
    }
  }
#pragma unroll
  for (int u = 0; u < COT; u++) {
    float v = acc[u];
    if (RELU_OUT) v = fmaxf(v, 0.f);
    y[(((size_t)(n * Cout + co0 + u)) * Hout + ho) * OW + wo] = v;
  }
}

// ---------------- conv 1x1 v4: 4 positions per thread ---------------------
template<int CIN, int COT, bool RELU_IN, bool ACCUM, bool RELU_OUT>
__global__ __launch_bounds__(256) void conv1x1_v4(
    const float* __restrict__ x, const float* __restrict__ w,
    const float* __restrict__ bias, float* __restrict__ y,
    int HW, int Cout) {
  const int p = (blockIdx.x * 256 + threadIdx.x) * 4;
  const int co0 = blockIdx.y * COT, n = blockIdx.z;

  float4 acc[COT];
#pragma unroll
  for (int u = 0; u < COT; u++) {
    const float b = bias[co0 + u];
    acc[u] = make_float4(b, b, b, b);
  }
  for (int ci = 0; ci < CIN; ci++) {
    float4 xv = *(const float4*)&x[((size_t)(n * CIN + ci)) * HW + p];
    if (RELU_IN) {
      xv.x = fmaxf(xv.x, 0.f); xv.y = fmaxf(xv.y, 0.f);
      xv.z = fmaxf(xv.z, 0.f); xv.w = fmaxf(xv.w, 0.f);
    }
#pragma unroll
    for (int u = 0; u < COT; u++) {
      const float wv = w[(co0 + u) * CIN + ci];
      acc[u].x = fmaf(xv.x, wv, acc[u].x);
      acc[u].y = fmaf(xv.y, wv, acc[u].y);
      acc[u].z = fmaf(xv.z, wv, acc[u].z);
      acc[u].w = fmaf(xv.w, wv, acc[u].w);
    }
  }
#pragma unroll
  for (int u = 0; u < COT; u++) {
    float4* yp = (float4*)&y[((size_t)(n * Cout + co0 + u)) * HW + p];
    float4 r = acc[u];
    if (ACCUM) {
      float4 h = *yp;
      r.x += h.x; r.y += h.y; r.z += h.z; r.w += h.w;
    }
    if (RELU_OUT) {
      r.x = fmaxf(r.x, 0.f); r.y = fmaxf(r.y, 0.f);
      r.z = fmaxf(r.z, 0.f); r.w = fmaxf(r.w, 0.f);
    }
    *yp = r;
  }
}

// ---------------- ConvTranspose 4x4 s2 p1 (generic, used for up1) ---------
template<int CIN, int COT, bool RELU_IN, bool RELU_OUT, int WH>
__global__ __launch_bounds__(256) void convt_row(
    const float* __restrict__ x, const float* __restrict__ w,
    const float* __restrict__ bias, float* __restrict__ y,
    int Hin, int Cout) {
  const int Hout = Hin * 2;
  const int t = blockIdx.x * 256 + threadIdx.x;
  const int a = t & (WH - 1);
  const int oh = rfl(t / WH);
  const int co0 = blockIdx.y * COT, n = blockIdx.z;

  float acc0[COT], acc1[COT];
#pragma unroll
  for (int u = 0; u < COT; u++) { acc0[u] = bias[co0 + u]; acc1[u] = bias[co0 + u]; }

  const int cm = a > 0 ? a - 1 : 0;
  const bool mm = a > 0;
  const int cp = a < WH - 1 ? a + 1 : WH - 1;
  const bool mp = a < WH - 1;

  const int kh0 = (oh + 1) & 1;
#pragma unroll
  for (int dh = 0; dh < 2; dh++) {
    const int kh = kh0 + 2 * dh;
    const int ih = (oh + 1 - kh) >> 1;
    if (ih >= 0 && ih < Hin) {
      for (int ci = 0; ci < CIN; ci++) {
        const float* row = x + (((size_t)(n * CIN + ci)) * Hin + ih) * WH;
        float x0  = row[a];
        float xm1 = row[cm];  xm1 = mm ? xm1 : 0.f;
        float xp1 = row[cp];  xp1 = mp ? xp1 : 0.f;
        if (RELU_IN) {
          x0 = fmaxf(x0, 0.f); xm1 = fmaxf(xm1, 0.f); xp1 = fmaxf(xp1, 0.f);
        }
        const float* wp = w + ((size_t)(ci * Cout + co0)) * 16 + kh * 4;
#pragma unroll
        for (int u = 0; u < COT; u++) {
          const float* wr = wp + u * 16;
          acc0[u] = fmaf(x0,  wr[1], acc0[u]);
          acc0[u] = fmaf(xm1, wr[3], acc0[u]);
          acc1[u] = fmaf(xp1, wr[0], acc1[u]);
          acc1[u] = fmaf(x0,  wr[2], acc1[u]);
        }
      }
    }
  }
#pragma unroll
  for (int u = 0; u < COT; u++) {
    float v0 = acc0[u], v1 = acc1[u];
    if (RELU_OUT) { v0 = fmaxf(v0, 0.f); v1 = fmaxf(v1, 0.f); }
    float* row = y + (((size_t)(n * Cout + co0 + u)) * Hout + oh) * (2 * WH);
    ((float2*)row)[a] = make_float2(v0, v1);
  }
}

// ---------------- VQ: codebook -> fp64 (+ norms), once per call -----------
__global__ __launch_bounds__(256) void cvt_cb(
    const float* __restrict__ cb, double* __restrict__ cb64,
    double* __restrict__ cbn64) {
  const int k = blockIdx.x * 256 + threadIdx.x;   // 0..511
  double s = 0.0;
  for (int d = 0; d < 64; d++) {
    const double c = (double)cb[d * 512 + k];
    cb64[k * 64 + d] = c;
    s = fma(c, c, s);
  }
  cbn64[k] = s;
}

// ---------------- VQ v3: scalar fp64 codebook, in-place quantize ----------
__global__ __launch_bounds__(256) void vq_kernel3(
    const float* __restrict__ cb, const double* __restrict__ cb64,
    const double* __restrict__ cbn64, float* __restrict__ zq) {
  __shared__ double redD[256];
  __shared__ int    redI[256];
  __shared__ int    bestIdx[64];
  const int tid = threadIdx.x;
  const int lane = tid & 63;
  const int g = rfl(tid >> 6);
  const int n = blockIdx.x >> 6, row = blockIdx.x & 63;
  float* zp = zq + ((size_t)n) * 262144 + (row << 6) + lane;

  double zr[64];
#pragma unroll
  for (int d = 0; d < 64; d++) zr[d] = (double)zp[(size_t)d * 4096];

  int best = 0;
  double bestd = 1e300;
  const double* cbk = cb64 + (size_t)g * 128 * 64;
  for (int j = 0; j < 128; j++) {
    const double* cw = cbk + j * 64;      // wave-uniform -> s_load
    double d0 = 0.0, d1 = 0.0, d2 = 0.0, d3 = 0.0;
#pragma unroll
    for (int d = 0; d < 64; d += 4) {
      d0 = fma(zr[d],     cw[d],     d0);
      d1 = fma(zr[d + 1], cw[d + 1], d1);
      d2 = fma(zr[d + 2], cw[d + 2], d2);
      d3 = fma(zr[d + 3], cw[d + 3], d3);
    }
    const int k = g * 128 + j;
    const double dist = cbn64[k] - 2.0 * ((d0 + d1) + (d2 + d3));
    if (dist < bestd) { bestd = dist; best = k; }
  }
  redD[tid] = bestd;
  redI[tid] = best;
  __syncthreads();
  if (tid < 64) {
    double bd = redD[lane];
    int bi = redI[lane];
#pragma unroll
    for (int gg = 1; gg < 4; gg++) {
      const double dd = redD[gg * 64 + lane];
      const int ii = redI[gg * 64 + lane];
      if (dd < bd || (dd == bd && ii < bi)) { bd = dd; bi = ii; }
    }
    bestIdx[lane] = bi;
  }
  __syncthreads();
  const int k = bestIdx[lane];
#pragma unroll
  for (int j = 0; j < 16; j++) {
    const int d = g * 16 + j;
    zp[(size_t)d * 4096] = cb[d * 512 + k];
  }
}

// -------------------------------------------------------------------------
extern "C" void kernel_launch(void* const* d_in, const int* in_sizes, int n_in,
                              void* d_out, int out_size, void* d_ws, size_t ws_size,
                              hipStream_t stream) {
  const float* x          = (const float*)d_in[0];
  const float* enc_w0     = (const float*)d_in[1];
  const float* enc_b0     = (const float*)d_in[2];
  const float* enc_w1     = (const float*)d_in[3];
  const float* enc_b1     = (const float*)d_in[4];
  const float* enc_wf     = (const float*)d_in[5];
  const float* enc_bf     = (const float*)d_in[6];
  const float* enc_res_w1 = (const float*)d_in[7];
  const float* enc_res_b1 = (const float*)d_in[8];
  const float* enc_res_w2 = (const float*)d_in[9];
  const float* enc_res_b2 = (const float*)d_in[10];
  const float* pre_w      = (const float*)d_in[11];
  const float* pre_b      = (const float*)d_in[12];
  const float* codebook   = (const float*)d_in[13];
  const float* dec_w      = (const float*)d_in[14];
  const float* dec_b      = (const float*)d_in[15];
  const float* dec_res_w1 = (const float*)d_in[16];
  const float* dec_res_b1 = (const float*)d_in[17];
  const float* dec_res_w2 = (const float*)d_in[18];
  const float* dec_res_b2 = (const float*)d_in[19];
  const float* up_w0      = (const float*)d_in[20];
  const float* up_b0      = (const float*)d_in[21];
  const float* up_w1      = (const float*)d_in[22];
  const float* up_b1      = (const float*)d_in[23];
  float* out = (float*)d_out;

  float* A = (float*)d_ws;         // 16,777,216 floats (64 MB)
  float* B = A + 16777216;         //  8,388,608 floats (32 MB)
  float* C = B + 8388608;          //  8,388,608 floats (32 MB)
  double* cb64  = (double*)(A + 6291456);          // 256 KB, VQ window only
  double* cbn64 = (double*)(A + 6291456 + 65536);  // 4 KB
  // conv3 weight packs in A's tail (floats 8.39M..). Written after conv1
  // (A dead then); later A writers stay below 4.2M floats; dead before up0.
  ushort* wpkF  = (ushort*)(A + 8388608);          // convf  294912 ush
  ushort* wpkEa = wpkF  + 294912;                  // enc r1a 73728
  ushort* wpkEb = wpkEa + 73728;                   // enc r1b 73728
  ushort* wpkD  = wpkEb + 73728;                   // dec    147456
  ushort* wpkDa = wpkD  + 147456;                  // dec r1a 73728
  ushort* wpkDb = wpkDa + 73728;                   // dec r1b 73728
  // C head: conv1 pack (dead once conv1 ran; convf then overwrites C),
  // later reused for up0 pack (written after pre, C dead then).
  ushort* wpk1  = (ushort*)C;                      // 262144 ush (512 KB)
  ushort* wpkT  = wpk1 + 262144;                   // 262144 ush

  const dim3 blk(256);
  const int N = 16;

  // --- conv1 weight prepack into C head (C untouched until convf) ---
  prep_w4<64, 128><<<dim3(64), blk, 0, stream>>>(enc_w1, wpk1);

  // --- Encoder ---
  conv4s2_row<3, 16, true, 128><<<dim3(64, 4, N), blk, 0, stream>>>(
      x, enc_w0, enc_b0, A, 128, 64);
  // conv1: MFMA stride-2 implicit GEMM, A -> B, ReLU out
  conv4s2_mfma<64, 128, true><<<dim3(64, 1, N), blk, 0, stream>>>(
      A, wpk1, enc_b1, B);

  // --- conv3 weight prepacks into A's tail (A dead: conv1 consumed it) ---
  prep_w3<128, 128><<<dim3(72), blk, 0, stream>>>(enc_wf, wpkF);
  prep_w3<128, 32><<<dim3(18), blk, 0, stream>>>(enc_res_w1, wpkEa);
  prep_w3<128, 32><<<dim3(18), blk, 0, stream>>>(
      enc_res_w1 + (size_t)32 * 128 * 9, wpkEb);
  prep_w3<64, 128><<<dim3(36), blk, 0, stream>>>(dec_w, wpkD);
  prep_w3<128, 32><<<dim3(18), blk, 0, stream>>>(dec_res_w1, wpkDa);
  prep_w3<128, 32><<<dim3(18), blk, 0, stream>>>(
      dec_res_w1 + (size_t)32 * 128 * 9, wpkDb);

  // convf: MFMA (input B already relu'd)
  conv3_mfma<128, 128, false><<<dim3(64, 1, N), blk, 0, stream>>>(
      B, wpkF, enc_bf, C);
  // enc res stack on C
  conv3_mfma<128, 32, true><<<dim3(64, 1, N), blk, 0, stream>>>(
      C, wpkEa, enc_res_b1, A);
  conv1x1_v4<32, 8, true, true, false><<<dim3(4, 16, N), blk, 0, stream>>>(
      A, enc_res_w2, enc_res_b2, C, 4096, 128);
  conv3_mfma<128, 32, true><<<dim3(64, 1, N), blk, 0, stream>>>(
      C, wpkEb, enc_res_b1 + 32, A);
  conv1x1_v4<32, 8, true, true, true><<<dim3(4, 16, N), blk, 0, stream>>>(
      A, enc_res_w2 + (size_t)128 * 32, enc_res_b2 + 128, C, 4096, 128);
  // pre: C already relu'd -> z in A
  conv1x1_v4<128, 8, false, false, false><<<dim3(4, 8, N), blk, 0, stream>>>(
      C, pre_w, pre_b, A, 4096, 64);

  // --- up0 weight prepack into C (C dead after pre) ---
  prep_wt<128, 64><<<dim3(64), blk, 0, stream>>>(up_w0, wpkT);

  // --- VQ (in-place on A; cb64 written here, after z, before use) ---
  cvt_cb<<<dim3(2), blk, 0, stream>>>(codebook, cb64, cbn64);
  vq_kernel3<<<dim3(1024), blk, 0, stream>>>(codebook, cb64, cbn64, A);

  // --- Decoder ---
  conv3_mfma<64, 128, false><<<dim3(64, 1, N), blk, 0, stream>>>(
      A, wpkD, dec_b, B);
  conv3_mfma<128, 32, true><<<dim3(64, 1, N), blk, 0, stream>>>(
      B, wpkDa, dec_res_b1, A);
  conv1x1_v4<32, 8, true, true, false><<<dim3(4, 16, N), blk, 0, stream>>>(
      A, dec_res_w2, dec_res_b2, B, 4096, 128);
  conv3_mfma<128, 32, true><<<dim3(64, 1, N), blk, 0, stream>>>(
      B, wpkDb, dec_res_b1 + 32, A);
  conv1x1_v4<32, 8, true, true, true><<<dim3(4, 16, N), blk, 0, stream>>>(
      A, dec_res_w2 + (size_t)128 * 32, dec_res_b2 + 128, B, 4096, 128);
  // up0: MFMA ConvTranspose, B (relu'd) -> A(16,64,128,128), ReLU out
  convt_mfma<128, 64, true><<<dim3(64, 1, N), blk, 0, stream>>>(
      B, wpkT, up_b0, A);
  // up1: A -> out(16,3,256,256)
  convt_row<64, 3, false, false, 128><<<dim3(128, 1, N), blk, 0, stream>>>(
      A, up_w1, up_b1, out, 128, 3);
}

// Round 5
// 1005.828 us; speedup vs baseline: 2.0978x; 1.1259x over previous
//
#include <hip/hip_runtime.h>
#include <math.h>

// -------------------------------------------------------------------------
// VQ-VAE forward, fp32, round 26: VQ distance GEMM moved to MFMA fp16x2.
//  - vq_mfma: dist = ||c||^2 - 2 z.c via mfma_f32_16x16x32_f16 with the
//    proven hi/lo*2^11 split (error ~1e-6 ~ numpy fp32 ref's own noise;
//    fp64 passing => margins > that noise). Block = (n,row); 4 waves x 16
//    positions; z frags in registers (no LDS); codebook prepacked to
//    A-frag order (128 KB, L2-resident); 4 groups x 128 entries with
//    per-lane argmin flush (k ascending => numpy tie-break), shfl_xor
//    reduce, in-place quantize. Norms fp64->fp32 once (cvt_cbn).
//  - Replaces fp64 vq_kernel3 (169 us) + cvt_cb.
//  - Everything else identical to R25 (1132 us, absmax 9.77e-4).
// Remaining fp32 VALU: conv0, 1x1s, up1.
// -------------------------------------------------------------------------

#define DEV __device__ __forceinline__

DEV int rfl(int v) { return __builtin_amdgcn_readfirstlane(v); }

DEV void async_copy16(const float* g, float* l) {
  __builtin_amdgcn_global_load_lds(
      (const __attribute__((address_space(1))) void*)g,
      (__attribute__((address_space(3))) void*)l, 16, 0, 0);
}

typedef __attribute__((ext_vector_type(8))) _Float16 h16x8;
typedef __attribute__((ext_vector_type(4))) float f32x4;

DEV ushort f2h(float f) {
  _Float16 h = (_Float16)f;
  return __builtin_bit_cast(ushort, h);
}
DEV float h2f(ushort u) { return (float)__builtin_bit_cast(_Float16, u); }
DEV uint pk(ushort a, ushort b) { return (uint)a | ((uint)b << 16); }

// ---------------- weight prepack for conv3_mfma ---------------------------
// Layout: [khkw 9][ch CIN/32][m COT/16][lane 64][hi8 | lo8] f16 (lo*2^11).
template<int CIN, int COT>
__global__ __launch_bounds__(256) void prep_w3(
    const float* __restrict__ w, ushort* __restrict__ wpk) {
  constexpr int nCh = CIN / 32, nM = COT / 16;
  const int t = blockIdx.x * 256 + threadIdx.x;
  if (t >= 9 * nCh * nM * 64) return;
  const int l = t & 63;
  int q = t >> 6;
  const int m = q % nM;  q /= nM;
  const int ch = q % nCh; q /= nCh;
  const int khkw = q;
  const int co = m * 16 + (l & 15);
  const int k8 = (l >> 4) * 8;
  ushort* o = wpk + (size_t)t * 16;
#pragma unroll
  for (int i = 0; i < 8; i++) {
    const int ci = ch * 32 + k8 + i;
    const float v = w[((size_t)co * CIN + ci) * 9 + khkw];
    const ushort hi = f2h(v);
    o[i]     = hi;
    o[8 + i] = f2h((v - h2f(hi)) * 2048.0f);
  }
}

// ---------------- weight prepack for conv4s2_mfma (4x4 OIHW) --------------
template<int CIN, int COT>
__global__ __launch_bounds__(256) void prep_w4(
    const float* __restrict__ w, ushort* __restrict__ wpk) {
  constexpr int nCh = CIN / 32, nM = COT / 16;
  const int t = blockIdx.x * 256 + threadIdx.x;
  if (t >= 16 * nCh * nM * 64) return;
  const int l = t & 63;
  int q = t >> 6;
  const int m = q % nM;  q /= nM;
  const int ch = q % nCh; q /= nCh;
  const int tap = q;
  const int co = m * 16 + (l & 15);
  const int k8 = (l >> 4) * 8;
  ushort* o = wpk + (size_t)t * 16;
#pragma unroll
  for (int i = 0; i < 8; i++) {
    const int ci = ch * 32 + k8 + i;
    const float v = w[((size_t)co * CIN + ci) * 16 + tap];
    const ushort hi = f2h(v);
    o[i]     = hi;
    o[8 + i] = f2h((v - h2f(hi)) * 2048.0f);
  }
}

// ---------------- weight prepack for convt_mfma (4x4, w[ci][co][kh][kw]) --
template<int CIN, int COT>
__global__ __launch_bounds__(256) void prep_wt(
    const float* __restrict__ w, ushort* __restrict__ wpk) {
  constexpr int nCh = CIN / 32, nM = COT / 16;
  const int t = blockIdx.x * 256 + threadIdx.x;
  if (t >= 16 * nCh * nM * 64) return;
  const int l = t & 63;
  int q = t >> 6;
  const int m = q % nM;  q /= nM;
  const int ch = q % nCh; q /= nCh;
  const int kh = q >> 2, kw = q & 3;
  const int co = m * 16 + (l & 15);
  const int k8 = (l >> 4) * 8;
  ushort* o = wpk + (size_t)t * 16;
#pragma unroll
  for (int i = 0; i < 8; i++) {
    const int ci = ch * 32 + k8 + i;
    const float v = w[(((size_t)ci * COT + co) * 4 + kh) * 4 + kw];
    const ushort hi = f2h(v);
    o[i]     = hi;
    o[8 + i] = f2h((v - h2f(hi)) * 2048.0f);
  }
}

// ---------------- codebook prepack for vq_mfma ----------------------------
// Layout: [chunk 2][m 32][lane 64][hi8 | lo8]; entry = m*16 + (l&15),
// d = chunk*32 + (l>>4)*8 + i. cb is (D=64, K=512) row-major.
__global__ __launch_bounds__(256) void prep_cb(
    const float* __restrict__ cb, ushort* __restrict__ cbpk) {
  const int t = blockIdx.x * 256 + threadIdx.x;   // 4096
  const int l = t & 63;
  const int m = (t >> 6) & 31;
  const int c = t >> 11;
  const int entry = m * 16 + (l & 15);
  ushort* o = cbpk + (size_t)t * 16;
#pragma unroll
  for (int i = 0; i < 8; i++) {
    const int d = c * 32 + (l >> 4) * 8 + i;
    const float v = cb[d * 512 + entry];
    const ushort hi = f2h(v);
    o[i]     = hi;
    o[8 + i] = f2h((v - h2f(hi)) * 2048.0f);
  }
}

// ---------------- codebook norms (fp64 accum -> fp32), once ---------------
__global__ __launch_bounds__(256) void cvt_cbn(
    const float* __restrict__ cb, float* __restrict__ cbn) {
  const int k = blockIdx.x * 256 + threadIdx.x;   // 0..511
  if (k >= 512) return;
  double s = 0.0;
  for (int d = 0; d < 64; d++) {
    const double c = (double)cb[d * 512 + k];
    s = fma(c, c, s);
  }
  cbn[k] = (float)s;
}

// ---------------- VQ via MFMA fp16x2: argmin + in-place quantize ----------
// Block = (n, row). 4 waves; wave w owns positions w*16..w*16+15.
// z B-frags in registers; codebook A-frags streamed from L2 (cbpk).
__global__ __launch_bounds__(256) void vq_mfma(
    const float* __restrict__ cb, const ushort* __restrict__ cbpk,
    const float* __restrict__ cbn, float* __restrict__ zq) {
  const int tid = threadIdx.x;
  const int l = tid & 63;
  const int w = rfl(tid >> 6);
  const int n = blockIdx.x >> 6, row = blockIdx.x & 63;
  float* zp = zq + (size_t)n * 262144 + row * 64;   // [d][64rows][64cols]
  const int pos = w * 16 + (l & 15);

  // z fragments: hi/lo per d-chunk (d = c*32 + (l>>4)*8 + i)
  h16x8 zh[2], zl[2];
#pragma unroll
  for (int c = 0; c < 2; c++) {
#pragma unroll
    for (int i = 0; i < 8; i++) {
      const int d = c * 32 + (l >> 4) * 8 + i;
      const float v = zp[(size_t)d * 4096 + pos];
      const _Float16 h = (_Float16)v;
      zh[c][i] = h;
      zl[c][i] = (_Float16)((v - (float)h) * 2048.0f);
    }
  }

  const float SCL = 1.0f / 2048.0f;
  float bestd = 1e30f;
  int best = 0;
  for (int grp = 0; grp < 4; grp++) {
    f32x4 aH[8], aM[8];
#pragma unroll
    for (int m = 0; m < 8; m++) {
      aH[m] = (f32x4){0.f, 0.f, 0.f, 0.f};
      aM[m] = (f32x4){0.f, 0.f, 0.f, 0.f};
    }
#pragma unroll
    for (int c = 0; c < 2; c++) {
#pragma unroll
      for (int m = 0; m < 8; m++) {
        const ushort* ap = cbpk + ((size_t)(c * 32 + grp * 8 + m) * 64 + l) * 16;
        const h16x8 ah = *(const h16x8*)ap;
        const h16x8 al = *(const h16x8*)(ap + 8);
        aH[m] = __builtin_amdgcn_mfma_f32_16x16x32_f16(ah, zh[c], aH[m], 0, 0, 0);
        aM[m] = __builtin_amdgcn_mfma_f32_16x16x32_f16(al, zh[c], aM[m], 0, 0, 0);
        aM[m] = __builtin_amdgcn_mfma_f32_16x16x32_f16(ah, zl[c], aM[m], 0, 0, 0);
      }
    }
    // argmin flush: entry k = grp*128 + m*16 + (l>>4)*4 + j (ascending)
#pragma unroll
    for (int m = 0; m < 8; m++) {
#pragma unroll
      for (int j = 0; j < 4; j++) {
        const int k = grp * 128 + m * 16 + ((l >> 4) << 2) + j;
        const float dd = aH[m][j] + aM[m][j] * SCL;
        const float dist = fmaf(-2.0f, dd, cbn[k]);
        if (dist < bestd) { bestd = dist; best = k; }
      }
    }
  }

  // reduce across the 4 lane-groups holding the same position
#pragma unroll
  for (int off = 16; off <= 32; off <<= 1) {
    const float d2 = __shfl_xor(bestd, off, 64);
    const int i2 = __shfl_xor(best, off, 64);
    if (d2 < bestd || (d2 == bestd && i2 < best)) { bestd = d2; best = i2; }
  }

  // in-place quantize: lane covers pos = w*16+(l&15), d = (l>>4)*16..+16
#pragma unroll
  for (int i = 0; i < 16; i++) {
    const int d = (l >> 4) * 16 + i;
    zp[(size_t)d * 4096 + pos] = cb[d * 512 + best];
  }
}

// ---------------- conv 4x4 s2 p1 via MFMA fp16x2 (128^2 -> 64^2) ----------
template<int CIN, int COT, bool RELU_OUT>
__global__ __launch_bounds__(256, 2) void conv4s2_mfma(
    const float* __restrict__ x, const ushort* __restrict__ wpk,
    const float* __restrict__ bias, float* __restrict__ y) {
  constexpr int nCh = CIN / 32, nM = COT / 16;
  constexpr int nStep = nCh * 2;
  __shared__ ushort lds[2][2][2][66][40];
  const int tid = threadIdx.x;
  const int l = tid & 63;
  const int wv = rfl(tid >> 6);
  const int ho = blockIdx.x;                  // output row 0..63
  const int n = blockIdx.z;

  {
    uint* lp = (uint*)&lds[0][0][0][0][0];
    for (int s = tid; s < 16 * 20; s += 256) {
      const int c = s / 20, w32 = s % 20;
      const int which = c & 1, rest = c >> 1;
      lp[(size_t)(rest * 66 + (which ? 65 : 0)) * 20 + w32] = 0;
    }
  }

  const float* xn = x + ((size_t)n * CIN) * 16384;

  float2 sreg[2][4][2];
  auto LOADG = [&](int step) {
    const int ch = step >> 1, h = step & 1;
#pragma unroll
    for (int rr = 0; rr < 2; rr++) {
      const int ir = 2 * ho - 1 + 2 * h + rr;
      const bool ok = (ir >= 0) && (ir < 128);
      const int irc = ok ? ir : 0;
#pragma unroll
      for (int cc = 0; cc < 4; cc++) {
        const int ci0 = ch * 32 + cc * 8 + wv * 2;
        float2 a = *(const float2*)(xn + (size_t)ci0 * 16384 + irc * 128 + 2 * l);
        float2 b = *(const float2*)(xn + (size_t)(ci0 + 1) * 16384 + irc * 128 + 2 * l);
        if (!ok) { a = make_float2(0.f, 0.f); b = make_float2(0.f, 0.f); }
        sreg[rr][cc][0] = a;
        sreg[rr][cc][1] = b;
      }
    }
  };
  auto WRITE = [&]() {
    uint* base = (uint*)&lds[0][0][0][0][0];
#pragma unroll
    for (int rr = 0; rr < 2; rr++) {
#pragma unroll
      for (int cc = 0; cc < 4; cc++) {
        const float e0 = sreg[rr][cc][0].x, o0 = sreg[rr][cc][0].y;
        const float e1 = sreg[rr][cc][1].x, o1 = sreg[rr][cc][1].y;
        const ushort he0 = f2h(e0), ho_0 = f2h(o0);
        const ushort he1 = f2h(e1), ho_1 = f2h(o1);
        const ushort le0 = f2h((e0 - h2f(he0)) * 2048.0f);
        const ushort lo0 = f2h((o0 - h2f(ho_0)) * 2048.0f);
        const ushort le1 = f2h((e1 - h2f(he1)) * 2048.0f);
        const ushort lo1 = f2h((o1 - h2f(ho_1)) * 2048.0f);
        const int u = cc * 4 + wv;
        const size_t sl20 = (size_t)(l + 1) * 20 + u;
        base[(size_t)((0 * 2 + rr) * 2 + 0) * 1320 + sl20] = pk(he0, he1);
        base[(size_t)((0 * 2 + rr) * 2 + 1) * 1320 + sl20] = pk(ho_0, ho_1);
        base[(size_t)((1 * 2 + rr) * 2 + 0) * 1320 + sl20] = pk(le0, le1);
        base[(size_t)((1 * 2 + rr) * 2 + 1) * 1320 + sl20] = pk(lo0, lo1);
      }
    }
  };

  f32x4 accH[nM], accM[nM];
#pragma unroll
  for (int m = 0; m < nM; m++) {
    const int co = m * 16 + ((l >> 4) << 2);
    accH[m] = (f32x4){bias[co], bias[co + 1], bias[co + 2], bias[co + 3]};
    accM[m] = (f32x4){0.f, 0.f, 0.f, 0.f};
  }

  const int pb = wv * 16;
  LOADG(0);
  for (int step = 0; step < nStep; step++) {
    __syncthreads();
    WRITE();
    if (step + 1 < nStep) LOADG(step + 1);
    __syncthreads();
    const int ch = step >> 1, h = step & 1;
#pragma unroll
    for (int rr = 0; rr < 2; rr++) {
      const int kh = 2 * h + rr;
#pragma unroll
      for (int kw = 0; kw < 4; kw++) {
        const int eo = (kw == 0 || kw == 2) ? 1 : 0;
        const int sh = (kw == 0) ? 0 : (kw == 3) ? 2 : 1;
        const int sl = pb + (l & 15) + sh;
        const h16x8 bh = *(const h16x8*)(&lds[0][rr][eo][sl][(l >> 4) * 8]);
        const h16x8 bl = *(const h16x8*)(&lds[1][rr][eo][sl][(l >> 4) * 8]);
        const ushort* wp = wpk + (((size_t)(kh * 4 + kw) * nCh + ch) * nM * 64 + l) * 16;
#pragma unroll
        for (int m = 0; m < nM; m++) {
          const h16x8 ah = *(const h16x8*)(wp + (size_t)m * 1024);
          const h16x8 al = *(const h16x8*)(wp + (size_t)m * 1024 + 8);
          accH[m] = __builtin_amdgcn_mfma_f32_16x16x32_f16(ah, bh, accH[m], 0, 0, 0);
          accM[m] = __builtin_amdgcn_mfma_f32_16x16x32_f16(al, bh, accM[m], 0, 0, 0);
          accM[m] = __builtin_amdgcn_mfma_f32_16x16x32_f16(ah, bl, accM[m], 0, 0, 0);
        }
      }
    }
  }

  const float SCL = 1.0f / 2048.0f;
  const int pos = pb + (l & 15);
  const int r4 = (l >> 4) << 2;
#pragma unroll
  for (int m = 0; m < nM; m++) {
    const int co = m * 16 + r4;
    float* yp = y + (((size_t)(n * COT + co)) * 64 + ho) * 64 + pos;
#pragma unroll
    for (int j = 0; j < 4; j++) {
      float v = accH[m][j] + accM[m][j] * SCL;
      if (RELU_OUT) v = fmaxf(v, 0.f);
      yp[(size_t)j * 4096] = v;
    }
  }
}

// ---------------- conv 3x3 s1 p1 via MFMA fp16x2 (64x64 imgs) -------------
template<int CIN, int COT, bool RELU_IN>
__global__ __launch_bounds__(256, 2) void conv3_mfma(
    const float* __restrict__ x, const ushort* __restrict__ wpk,
    const float* __restrict__ bias, float* __restrict__ y) {
  constexpr int nCh = CIN / 32, nM = COT / 16;
  __shared__ ushort lds[2][2][3 * 66 * 40];   // 63,360 B
  const int tid = threadIdx.x;
  const int l = tid & 63;
  const int wv = rfl(tid >> 6);               // 0..3
  const int r = blockIdx.x;                   // output row 0..63
  const int n = blockIdx.z;

  {
    uint* lp = (uint*)&lds[0][0][0];
    for (int s = tid; s < 24 * 20; s += 256) {
      const int slot = s / 20, w32 = s % 20;
      const int which = slot & 1;
      const int rowrel = (slot >> 1) % 3;
      const int plane  = ((slot >> 1) / 3) & 1;
      const int buf    = (slot >> 1) / 6;
      lp[(size_t)((buf * 2 + plane) * 198 + rowrel * 66 + (which ? 65 : 0)) * 20 + w32] = 0;
    }
  }

  const float* xn = x + ((size_t)n * CIN) * 4096;

  float sreg[3][4][2];
  auto LOADG = [&](int ch) {
#pragma unroll
    for (int rr = 0; rr < 3; rr++) {
      const int ir = r - 1 + rr;
      const bool ok = (ir >= 0) && (ir < 64);
#pragma unroll
      for (int cc = 0; cc < 4; cc++) {
        const int ci0 = ch * 32 + cc * 8 + wv * 2;
        sreg[rr][cc][0] = ok ? xn[((size_t)ci0 * 64 + ir) * 64 + l] : 0.f;
        sreg[rr][cc][1] = ok ? xn[((size_t)(ci0 + 1) * 64 + ir) * 64 + l] : 0.f;
      }
    }
  };
  auto WRITE = [&](int buf) {
    uint* ph = (uint*)&lds[buf][0][0];
    uint* pl = (uint*)&lds[buf][1][0];
#pragma unroll
    for (int rr = 0; rr < 3; rr++) {
#pragma unroll
      for (int cc = 0; cc < 4; cc++) {
        float v0 = sreg[rr][cc][0], v1 = sreg[rr][cc][1];
        if (RELU_IN) { v0 = fmaxf(v0, 0.f); v1 = fmaxf(v1, 0.f); }
        const ushort h0 = f2h(v0), h1 = f2h(v1);
        const ushort m0 = f2h((v0 - h2f(h0)) * 2048.0f);
        const ushort m1 = f2h((v1 - h2f(h1)) * 2048.0f);
        const int idx = (rr * 66 + (l + 1)) * 20 + cc * 4 + wv;   // u32 index
        ph[idx] = (uint)h0 | ((uint)h1 << 16);
        pl[idx] = (uint)m0 | ((uint)m1 << 16);
      }
    }
  };

  f32x4 accH[nM], accM[nM];
#pragma unroll
  for (int m = 0; m < nM; m++) {
    const int co = m * 16 + ((l >> 4) << 2);
    accH[m] = (f32x4){bias[co], bias[co + 1], bias[co + 2], bias[co + 3]};
    accM[m] = (f32x4){0.f, 0.f, 0.f, 0.f};
  }

  const int pb = wv * 16;          // this wave's position base
  LOADG(0); WRITE(0);
  if (nCh > 1) LOADG(1);
  int cur = 0;
  for (int ch = 0; ch < nCh; ch++) {
    __syncthreads();
    const ushort* base_h = &lds[cur][0][0];
    const ushort* base_l = &lds[cur][1][0];
#pragma unroll
    for (int kh = 0; kh < 3; kh++) {
#pragma unroll
      for (int kw = 0; kw < 3; kw++) {
        const int slot = kh * 66 + pb + (l & 15) + kw;
        const h16x8 bh = *(const h16x8*)(base_h + slot * 40 + (l >> 4) * 8);
        const h16x8 bl = *(const h16x8*)(base_l + slot * 40 + (l >> 4) * 8);
        const ushort* wp = wpk + (((size_t)(kh * 3 + kw) * nCh + ch) * nM * 64 + l) * 16;
#pragma unroll
        for (int m = 0; m < nM; m++) {
          const h16x8 ah = *(const h16x8*)(wp + (size_t)m * 1024);
          const h16x8 al = *(const h16x8*)(wp + (size_t)m * 1024 + 8);
          accH[m] = __builtin_amdgcn_mfma_f32_16x16x32_f16(ah, bh, accH[m], 0, 0, 0);
          accM[m] = __builtin_amdgcn_mfma_f32_16x16x32_f16(al, bh, accM[m], 0, 0, 0);
          accM[m] = __builtin_amdgcn_mfma_f32_16x16x32_f16(ah, bl, accM[m], 0, 0, 0);
        }
      }
    }
    if (ch + 1 < nCh) {
      WRITE(cur ^ 1);
      if (ch + 2 < nCh) LOADG(ch + 2);
    }
    cur ^= 1;
  }

  const float SCL = 1.0f / 2048.0f;
  const int pos = pb + (l & 15);
  const int r4 = (l >> 4) << 2;
#pragma unroll
  for (int m = 0; m < nM; m++) {
    const int co = m * 16 + r4;
    float* yp = y + (((size_t)(n * COT + co)) * 64 + r) * 64 + pos;
#pragma unroll
    for (int j = 0; j < 4; j++)
      yp[(size_t)j * 4096] = accH[m][j] + accM[m][j] * SCL;
  }
}

// ---------------- ConvTranspose 4x4 s2 p1 via MFMA fp16x2 (up0) -----------
template<int CIN, int COT, bool RELU_OUT>
__global__ __launch_bounds__(256, 2) void convt_mfma(
    const float* __restrict__ x, const ushort* __restrict__ wpk,
    const float* __restrict__ bias, float* __restrict__ y) {
  constexpr int nCh = CIN / 32, nM = COT / 16;
  __shared__ ushort lds[2][2][3 * 66 * 40];
  const int tid = threadIdx.x;
  const int l = tid & 63;
  const int wv = rfl(tid >> 6);
  const int a = blockIdx.x;                   // input row 0..63
  const int n = blockIdx.z;

  {
    uint* lp = (uint*)&lds[0][0][0];
    for (int s = tid; s < 24 * 20; s += 256) {
      const int slot = s / 20, w32 = s % 20;
      const int which = slot & 1;
      const int rowrel = (slot >> 1) % 3;
      const int plane  = ((slot >> 1) / 3) & 1;
      const int buf    = (slot >> 1) / 6;
      lp[(size_t)((buf * 2 + plane) * 198 + rowrel * 66 + (which ? 65 : 0)) * 20 + w32] = 0;
    }
  }

  const float* xn = x + ((size_t)n * CIN) * 4096;

  float sreg[3][4][2];
  auto LOADG = [&](int ch) {
#pragma unroll
    for (int rr = 0; rr < 3; rr++) {
      const int ir = a - 1 + rr;
      const bool ok = (ir >= 0) && (ir < 64);
#pragma unroll
      for (int cc = 0; cc < 4; cc++) {
        const int ci0 = ch * 32 + cc * 8 + wv * 2;
        sreg[rr][cc][0] = ok ? xn[((size_t)ci0 * 64 + ir) * 64 + l] : 0.f;
        sreg[rr][cc][1] = ok ? xn[((size_t)(ci0 + 1) * 64 + ir) * 64 + l] : 0.f;
      }
    }
  };
  auto WRITE = [&](int buf) {
    uint* ph = (uint*)&lds[buf][0][0];
    uint* pl = (uint*)&lds[buf][1][0];
#pragma unroll
    for (int rr = 0; rr < 3; rr++) {
#pragma unroll
      for (int cc = 0; cc < 4; cc++) {
        const float v0 = sreg[rr][cc][0], v1 = sreg[rr][cc][1];
        const ushort h0 = f2h(v0), h1 = f2h(v1);
        const ushort m0 = f2h((v0 - h2f(h0)) * 2048.0f);
        const ushort m1 = f2h((v1 - h2f(h1)) * 2048.0f);
        const int idx = (rr * 66 + (l + 1)) * 20 + cc * 4 + wv;
        ph[idx] = (uint)h0 | ((uint)h1 << 16);
        pl[idx] = (uint)m0 | ((uint)m1 << 16);
      }
    }
  };

  f32x4 aH[4][nM], aM[4][nM];
#pragma unroll
  for (int m = 0; m < nM; m++) {
    const int co = m * 16 + ((l >> 4) << 2);
    const f32x4 b4 = (f32x4){bias[co], bias[co + 1], bias[co + 2], bias[co + 3]};
#pragma unroll
    for (int o = 0; o < 4; o++) { aH[o][m] = b4; aM[o][m] = (f32x4){0.f,0.f,0.f,0.f}; }
  }

  const int pb = wv * 16;
  LOADG(0); WRITE(0);
  if (nCh > 1) LOADG(1);
  int cur = 0;

#define CT_APPLY(OIDX, KH, KW) {                                              \
    const ushort* wp_ = wpk + (((size_t)((KH) * 4 + (KW)) * nCh + ch) * nM * 64 + l) * 16; \
    _Pragma("unroll")                                                         \
    for (int m = 0; m < nM; m++) {                                            \
      const h16x8 ah = *(const h16x8*)(wp_ + (size_t)m * 1024);               \
      const h16x8 al = *(const h16x8*)(wp_ + (size_t)m * 1024 + 8);           \
      aH[OIDX][m] = __builtin_amdgcn_mfma_f32_16x16x32_f16(ah, bh, aH[OIDX][m], 0, 0, 0); \
      aM[OIDX][m] = __builtin_amdgcn_mfma_f32_16x16x32_f16(al, bh, aM[OIDX][m], 0, 0, 0); \
      aM[OIDX][m] = __builtin_amdgcn_mfma_f32_16x16x32_f16(ah, bl, aM[OIDX][m], 0, 0, 0); \
    }}
#define CT_FRAG(RR, DD)                                                       \
    const int slot = (RR) * 66 + pb + (l & 15) + 1 + (DD);                    \
    const h16x8 bh = *(const h16x8*)(base_h + slot * 40 + (l >> 4) * 8);      \
    const h16x8 bl = *(const h16x8*)(base_l + slot * 40 + (l >> 4) * 8);

  for (int ch = 0; ch < nCh; ch++) {
    __syncthreads();
    const ushort* base_h = &lds[cur][0][0];
    const ushort* base_l = &lds[cur][1][0];
    { CT_FRAG(0, -1) CT_APPLY(0, 3, 3) }
    { CT_FRAG(0,  0) CT_APPLY(0, 3, 1) CT_APPLY(1, 3, 2) }
    { CT_FRAG(0, +1) CT_APPLY(1, 3, 0) }
    { CT_FRAG(1, -1) CT_APPLY(0, 1, 3) CT_APPLY(2, 2, 3) }
    { CT_FRAG(1,  0) CT_APPLY(0, 1, 1) CT_APPLY(1, 1, 2) CT_APPLY(2, 2, 1) CT_APPLY(3, 2, 2) }
    { CT_FRAG(1, +1) CT_APPLY(1, 1, 0) CT_APPLY(3, 2, 0) }
    { CT_FRAG(2, -1) CT_APPLY(2, 0, 3) }
    { CT_FRAG(2,  0) CT_APPLY(2, 0, 1) CT_APPLY(3, 0, 2) }
    { CT_FRAG(2, +1) CT_APPLY(3, 0, 0) }
    if (ch + 1 < nCh) {
      WRITE(cur ^ 1);
      if (ch + 2 < nCh) LOADG(ch + 2);
    }
    cur ^= 1;
  }
#undef CT_APPLY
#undef CT_FRAG

  const float SCL = 1.0f / 2048.0f;
  const int b = pb + (l & 15);
  const int oh0 = 2 * a;
  const int r4 = (l >> 4) << 2;
#pragma unroll
  for (int m = 0; m < nM; m++) {
    const int co = m * 16 + r4;
#pragma unroll
    for (int j = 0; j < 4; j++) {
      float v0e = aH[0][m][j] + aM[0][m][j] * SCL;
      float v0o = aH[1][m][j] + aM[1][m][j] * SCL;
      float v1e = aH[2][m][j] + aM[2][m][j] * SCL;
      float v1o = aH[3][m][j] + aM[3][m][j] * SCL;
      if (RELU_OUT) {
        v0e = fmaxf(v0e, 0.f); v0o = fmaxf(v0o, 0.f);
        v1e = fmaxf(v1e, 0.f); v1o = fmaxf(v1o, 0.f);
      }
      float* row0 = y + (((size_t)(n * COT + co + j)) * 128 + oh0) * 128;
      ((float2*)row0)[b] = make_float2(v0e, v0o);
      ((float2*)(row0 + 128))[b] = make_float2(v1e, v1o);
    }
  }
}

// ---------------- conv 4x4 stride2 pad1 (generic, used for conv0) ---------
template<int CIN, int COT, bool RELU_OUT, int OW>
__global__ __launch_bounds__(256) void conv4s2_row(
    const float* __restrict__ x, const float* __restrict__ w,
    const float* __restrict__ bias, float* __restrict__ y,
    int Hout, int Cout) {
  const int Win = OW * 2, Hin = Hout * 2;
  const int t = blockIdx.x * 256 + threadIdx.x;
  const int wo = t & (OW - 1);
  const int ho = rfl(t / OW);
  const int co0 = blockIdx.y * COT, n = blockIdx.z;

  float acc[COT];
#pragma unroll
  for (int u = 0; u < COT; u++) acc[u] = bias[co0 + u];

  const int iw0 = 2 * wo - 1;
  const int cA = iw0 < 0 ? 0 : iw0;
  const bool mA = iw0 >= 0;
  const int cD = (iw0 + 3 < Win) ? iw0 + 3 : Win - 1;
  const bool mD = iw0 + 3 < Win;

  for (int ci = 0; ci < CIN; ci++) {
    const float* xp = x + ((size_t)(n * CIN + ci)) * Hin * Win;
    const float* wp = w + ((size_t)(co0 * CIN + ci)) * 16;
#pragma unroll
    for (int kh = 0; kh < 4; kh++) {
      const int ih = 2 * ho - 1 + kh;
      if (ih >= 0 && ih < Hin) {
        const float* row = xp + (size_t)ih * Win;
        float x0 = row[cA];      x0 = mA ? x0 : 0.f;
        float x1 = row[iw0 + 1];
        float x2 = row[iw0 + 2];
        float x3 = row[cD];      x3 = mD ? x3 : 0.f;
#pragma unroll
        for (int u = 0; u < COT; u++) {
          const float* wr = wp + u * CIN * 16 + kh * 4;
          acc[u] = fmaf(x0, wr[0], acc[u]);
          acc[u] = fmaf(x1, wr[1], acc[u]);
          acc[u] = fmaf(x2, wr[2], acc[u]);
          acc[u] = fmaf(x3, wr[3], acc[u]);
        }
      }
    }
  }
#pragma unroll
  for (int u = 0; u < COT; u++) {
    float v = acc[u];
    if (RELU_OUT) v = fmaxf(v, 0.f);
    y[(((size_t)(n * Cout + co0 + u)) * Hout + ho) * OW + wo] = v;
  }
}

// ---------------- conv 1x1 v4: 4 positions per thread ---------------------
template<int CIN, int COT, bool RELU_IN, bool ACCUM, bool RELU_OUT>
__global__ __launch_bounds__(256) void conv1x1_v4(
    const float* __restrict__ x, const float* __restrict__ w,
    const float* __restrict__ bias, float* __restrict__ y,
    int HW, int Cout) {
  const int p = (blockIdx.x * 256 + threadIdx.x) * 4;
  const int co0 = blockIdx.y * COT, n = blockIdx.z;

  float4 acc[COT];
#pragma unroll
  for (int u = 0; u < COT; u++) {
    const float b = bias[co0 + u];
    acc[u] = make_float4(b, b, b, b);
  }
  for (int ci = 0; ci < CIN; ci++) {
    float4 xv = *(const float4*)&x[((size_t)(n * CIN + ci)) * HW + p];
    if (RELU_IN) {
      xv.x = fmaxf(xv.x, 0.f); xv.y = fmaxf(xv.y, 0.f);
      xv.z = fmaxf(xv.z, 0.f); xv.w = fmaxf(xv.w, 0.f);
    }
#pragma unroll
    for (int u = 0; u < COT; u++) {
      const float wv = w[(co0 + u) * CIN + ci];
      acc[u].x = fmaf(xv.x, wv, acc[u].x);
      acc[u].y = fmaf(xv.y, wv, acc[u].y);
      acc[u].z = fmaf(xv.z, wv, acc[u].z);
      acc[u].w = fmaf(xv.w, wv, acc[u].w);
    }
  }
#pragma unroll
  for (int u = 0; u < COT; u++) {
    float4* yp = (float4*)&y[((size_t)(n * Cout + co0 + u)) * HW + p];
    float4 r = acc[u];
    if (ACCUM) {
      float4 h = *yp;
      r.x += h.x; r.y += h.y; r.z += h.z; r.w += h.w;
    }
    if (RELU_OUT) {
      r.x = fmaxf(r.x, 0.f); r.y = fmaxf(r.y, 0.f);
      r.z = fmaxf(r.z, 0.f); r.w = fmaxf(r.w, 0.f);
    }
    *yp = r;
  }
}

// ---------------- ConvTranspose 4x4 s2 p1 (generic, used for up1) ---------
template<int CIN, int COT, bool RELU_IN, bool RELU_OUT, int WH>
__global__ __launch_bounds__(256) void convt_row(
    const float* __restrict__ x, const float* __restrict__ w,
    const float* __restrict__ bias, float* __restrict__ y,
    int Hin, int Cout) {
  const int Hout = Hin * 2;
  const int t = blockIdx.x * 256 + threadIdx.x;
  const int a = t & (WH - 1);
  const int oh = rfl(t / WH);
  const int co0 = blockIdx.y * COT, n = blockIdx.z;

  float acc0[COT], acc1[COT];
#pragma unroll
  for (int u = 0; u < COT; u++) { acc0[u] = bias[co0 + u]; acc1[u] = bias[co0 + u]; }

  const int cm = a > 0 ? a - 1 : 0;
  const bool mm = a > 0;
  const int cp = a < WH - 1 ? a + 1 : WH - 1;
  const bool mp = a < WH - 1;

  const int kh0 = (oh + 1) & 1;
#pragma unroll
  for (int dh = 0; dh < 2; dh++) {
    const int kh = kh0 + 2 * dh;
    const int ih = (oh + 1 - kh) >> 1;
    if (ih >= 0 && ih < Hin) {
      for (int ci = 0; ci < CIN; ci++) {
        const float* row = x + (((size_t)(n * CIN + ci)) * Hin + ih) * WH;
        float x0  = row[a];
        float xm1 = row[cm];  xm1 = mm ? xm1 : 0.f;
        float xp1 = row[cp];  xp1 = mp ? xp1 : 0.f;
        if (RELU_IN) {
          x0 = fmaxf(x0, 0.f); xm1 = fmaxf(xm1, 0.f); xp1 = fmaxf(xp1, 0.f);
        }
        const float* wp = w + ((size_t)(ci * Cout + co0)) * 16 + kh * 4;
#pragma unroll
        for (int u = 0; u < COT; u++) {
          const float* wr = wp + u * 16;
          acc0[u] = fmaf(x0,  wr[1], acc0[u]);
          acc0[u] = fmaf(xm1, wr[3], acc0[u]);
          acc1[u] = fmaf(xp1, wr[0], acc1[u]);
          acc1[u] = fmaf(x0,  wr[2], acc1[u]);
        }
      }
    }
  }
#pragma unroll
  for (int u = 0; u < COT; u++) {
    float v0 = acc0[u], v1 = acc1[u];
    if (RELU_OUT) { v0 = fmaxf(v0, 0.f); v1 = fmaxf(v1, 0.f); }
    float* row = y + (((size_t)(n * Cout + co0 + u)) * Hout + oh) * (2 * WH);
    ((float2*)row)[a] = make_float2(v0, v1);
  }
}

// -------------------------------------------------------------------------
extern "C" void kernel_launch(void* const* d_in, const int* in_sizes, int n_in,
                              void* d_out, int out_size, void* d_ws, size_t ws_size,
                              hipStream_t stream) {
  const float* x          = (const float*)d_in[0];
  const float* enc_w0     = (const float*)d_in[1];
  const float* enc_b0     = (const float*)d_in[2];
  const float* enc_w1     = (const float*)d_in[3];
  const float* enc_b1     = (const float*)d_in[4];
  const float* enc_wf     = (const float*)d_in[5];
  const float* enc_bf     = (const float*)d_in[6];
  const float* enc_res_w1 = (const float*)d_in[7];
  const float* enc_res_b1 = (const float*)d_in[8];
  const float* enc_res_w2 = (const float*)d_in[9];
  const float* enc_res_b2 = (const float*)d_in[10];
  const float* pre_w      = (const float*)d_in[11];
  const float* pre_b      = (const float*)d_in[12];
  const float* codebook   = (const float*)d_in[13];
  const float* dec_w      = (const float*)d_in[14];
  const float* dec_b      = (const float*)d_in[15];
  const float* dec_res_w1 = (const float*)d_in[16];
  const float* dec_res_b1 = (const float*)d_in[17];
  const float* dec_res_w2 = (const float*)d_in[18];
  const float* dec_res_b2 = (const float*)d_in[19];
  const float* up_w0      = (const float*)d_in[20];
  const float* up_b0      = (const float*)d_in[21];
  const float* up_w1      = (const float*)d_in[22];
  const float* up_b1      = (const float*)d_in[23];
  float* out = (float*)d_out;

  float* A = (float*)d_ws;         // 16,777,216 floats (64 MB)
  float* B = A + 16777216;         //  8,388,608 floats (32 MB)
  float* C = B + 8388608;          //  8,388,608 floats (32 MB)
  // conv3 weight packs + VQ packs in A's tail (floats 8.39M..). Written
  // after conv1 (A dead then); later A writers stay below 4.2M floats;
  // dead before up0 rewrites A.
  ushort* wpkF  = (ushort*)(A + 8388608);          // convf  294912 ush
  ushort* wpkEa = wpkF  + 294912;                  // enc r1a 73728
  ushort* wpkEb = wpkEa + 73728;                   // enc r1b 73728
  ushort* wpkD  = wpkEb + 73728;                   // dec    147456
  ushort* wpkDa = wpkD  + 147456;                  // dec r1a 73728
  ushort* wpkDb = wpkDa + 73728;                   // dec r1b 73728
  ushort* cbpk  = wpkDb + 73728;                   // vq cb pack 131072 ush
  float*  cbn   = (float*)(cbpk + 131072);         // 512 floats
  // C head: conv1 pack (dead once conv1 ran; convf then overwrites C),
  // later reused for up0 pack (written after pre, C dead then).
  ushort* wpk1  = (ushort*)C;                      // 262144 ush (512 KB)
  ushort* wpkT  = wpk1 + 262144;                   // 262144 ush

  const dim3 blk(256);
  const int N = 16;

  // --- conv1 weight prepack into C head (C untouched until convf) ---
  prep_w4<64, 128><<<dim3(64), blk, 0, stream>>>(enc_w1, wpk1);

  // --- Encoder ---
  conv4s2_row<3, 16, true, 128><<<dim3(64, 4, N), blk, 0, stream>>>(
      x, enc_w0, enc_b0, A, 128, 64);
  // conv1: MFMA stride-2 implicit GEMM, A -> B, ReLU out
  conv4s2_mfma<64, 128, true><<<dim3(64, 1, N), blk, 0, stream>>>(
      A, wpk1, enc_b1, B);

  // --- prepacks into A's tail (A dead: conv1 consumed it) ---
  prep_w3<128, 128><<<dim3(72), blk, 0, stream>>>(enc_wf, wpkF);
  prep_w3<128, 32><<<dim3(18), blk, 0, stream>>>(enc_res_w1, wpkEa);
  prep_w3<128, 32><<<dim3(18), blk, 0, stream>>>(
      enc_res_w1 + (size_t)32 * 128 * 9, wpkEb);
  prep_w3<64, 128><<<dim3(36), blk, 0, stream>>>(dec_w, wpkD);
  prep_w3<128, 32><<<dim3(18), blk, 0, stream>>>(dec_res_w1, wpkDa);
  prep_w3<128, 32><<<dim3(18), blk, 0, stream>>>(
      dec_res_w1 + (size_t)32 * 128 * 9, wpkDb);
  prep_cb<<<dim3(16), blk, 0, stream>>>(codebook, cbpk);
  cvt_cbn<<<dim3(2), blk, 0, stream>>>(codebook, cbn);

  // convf: MFMA (input B already relu'd)
  conv3_mfma<128, 128, false><<<dim3(64, 1, N), blk, 0, stream>>>(
      B, wpkF, enc_bf, C);
  // enc res stack on C
  conv3_mfma<128, 32, true><<<dim3(64, 1, N), blk, 0, stream>>>(
      C, wpkEa, enc_res_b1, A);
  conv1x1_v4<32, 8, true, true, false><<<dim3(4, 16, N), blk, 0, stream>>>(
      A, enc_res_w2, enc_res_b2, C, 4096, 128);
  conv3_mfma<128, 32, true><<<dim3(64, 1, N), blk, 0, stream>>>(
      C, wpkEb, enc_res_b1 + 32, A);
  conv1x1_v4<32, 8, true, true, true><<<dim3(4, 16, N), blk, 0, stream>>>(
      A, enc_res_w2 + (size_t)128 * 32, enc_res_b2 + 128, C, 4096, 128);
  // pre: C already relu'd -> z in A
  conv1x1_v4<128, 8, false, false, false><<<dim3(4, 8, N), blk, 0, stream>>>(
      C, pre_w, pre_b, A, 4096, 64);

  // --- up0 weight prepack into C (C dead after pre) ---
  prep_wt<128, 64><<<dim3(64), blk, 0, stream>>>(up_w0, wpkT);

  // --- VQ (in-place on A) via MFMA ---
  vq_mfma<<<dim3(1024), blk, 0, stream>>>(codebook, cbpk, cbn, A);

  // --- Decoder ---
  conv3_mfma<64, 128, false><<<dim3(64, 1, N), blk, 0, stream>>>(
      A, wpkD, dec_b, B);
  conv3_mfma<128, 32, true><<<dim3(64, 1, N), blk, 0, stream>>>(
      B, wpkDa, dec_res_b1, A);
  conv1x1_v4<32, 8, true, true, false><<<dim3(4, 16, N), blk, 0, stream>>>(
      A, dec_res_w2, dec_res_b2, B, 4096, 128);
  conv3_mfma<128, 32, true><<<dim3(64, 1, N), blk, 0, stream>>>(
      B, wpkDb, dec_res_b1 + 32, A);
  conv1x1_v4<32, 8, true, true, true><<<dim3(4, 16, N), blk, 0, stream>>>(
      A, dec_res_w2 + (size_t)128 * 32, dec_res_b2 + 128, B, 4096, 128);
  // up0: MFMA ConvTranspose, B (relu'd) -> A(16,64,128,128), ReLU out
  convt_mfma<128, 64, true><<<dim3(64, 1, N), blk, 0, stream>>>(
      B, wpkT, up_b0, A);
  // up1: A -> out(16,3,256,256)
  convt_row<64, 3, false, false, 128><<<dim3(128, 1, N), blk, 0, stream>>>(
      A, up_w1, up_b1, out, 128, 3);
}